// Round 2
// baseline (490.710 us; speedup 1.0000x reference)
//
#include <hip/hip_runtime.h>
#include <hip/hip_fp16.h>

typedef _Float16 half8 __attribute__((ext_vector_type(8)));
typedef float floatx4 __attribute__((ext_vector_type(4)));

// ---------------- degree init (+ zero the 8 partition cursors) ----------------
__global__ __launch_bounds__(256) void deg_init_k(int* __restrict__ deg, int n,
                                                  int* __restrict__ scnt) {
    int i = blockIdx.x * 256 + threadIdx.x;
    if (i < n) deg[i] = 1;  // self-loop
    if (blockIdx.x == 0 && threadIdx.x < 8) scnt[threadIdx.x] = 0;
}

__global__ __launch_bounds__(256) void dinv_k(const int* __restrict__ deg,
                                              float* __restrict__ dinv, int n) {
    int i = blockIdx.x * 256 + threadIdx.x;
    if (i < n) dinv[i] = rsqrtf((float)deg[i]);
}

// ---------------- weight convert + transpose: Wt[n][k] = (half)W[k][n] ----------
__global__ __launch_bounds__(256) void wconv_k(const float* __restrict__ W1,
                                               const float* __restrict__ W2,
                                               const float* __restrict__ W3,
                                               __half* __restrict__ Wt1,
                                               __half* __restrict__ Wt2,
                                               __half* __restrict__ Wt3) {
    int idx = blockIdx.x * 256 + threadIdx.x;
    if (idx < 16384) {
        int k = idx >> 7, nn = idx & 127;
        Wt1[nn * 128 + k] = __float2half(W1[idx]);
    } else if (idx < 32768) {
        int j = idx - 16384;
        int k = j >> 7, nn = j & 127;
        Wt2[nn * 128 + k] = __float2half(W2[j]);
    } else if (idx < 40960) {
        int j = idx - 32768;
        int k = j >> 6, nn = j & 63;
        Wt3[nn * 128 + k] = __float2half(W3[j]);
    }
}

// ---------------- pass 1: partition edges into 8 dst-chunk streams -------------
// Single sweep of the edge list (vs 8x in the old one-pass fill). Per 256-edge
// block-batch: LDS-count per chunk, 8 global atomicAdds for bases, then each
// thread writes its packed (d,s) pair into its chunk's staging stream. Writes
// are dense within per-block 256B sub-regions -> full-line writebacks.
// Also fuses the degree count (replaces deg_count_k).
__global__ __launch_bounds__(256) void part_k(const int* __restrict__ row,
                                              const int* __restrict__ col, int E, int N,
                                              int* __restrict__ deg,
                                              unsigned long long* __restrict__ stg,
                                              int cap, int* __restrict__ scnt) {
    __shared__ int lcnt[8];
    __shared__ int lbase[8];
    int tid = threadIdx.x;
    int chunk = (N + 7) >> 3;
    for (int base = blockIdx.x * 256; base < E; base += gridDim.x * 256) {
        int i = base + tid;
        if (tid < 8) lcnt[tid] = 0;
        __syncthreads();
        int s = 0, d = 0, c = 0, r = 0;
        bool v = i < E;
        if (v) {
            s = row[i];
            d = col[i];
            atomicAdd(&deg[d], 1);
            c = d / chunk;
            r = atomicAdd(&lcnt[c], 1);
        }
        __syncthreads();
        if (tid < 8) lbase[tid] = atomicAdd(&scnt[tid], lcnt[tid]);
        __syncthreads();
        if (v) {
            int slot = lbase[c] + r;
            if (slot < cap)
                stg[(size_t)c * cap + slot] =
                    ((unsigned long long)(unsigned)d << 32) | (unsigned)s;
        }
    }
}

// ---------------- 3-phase exclusive scan of deg -> col_ptr ----------------
__global__ __launch_bounds__(256) void scan_p1(const int* __restrict__ deg, int n,
                                               int* __restrict__ bsum) {
    __shared__ int lds[256];
    int t = threadIdx.x;
    int base = blockIdx.x * 1024 + t * 4;
    int s = 0;
#pragma unroll
    for (int i = 0; i < 4; i++) {
        int idx = base + i;
        if (idx < n) s += deg[idx];
    }
    lds[t] = s;
    __syncthreads();
    for (int o = 128; o > 0; o >>= 1) {
        if (t < o) lds[t] += lds[t + o];
        __syncthreads();
    }
    if (t == 0) bsum[blockIdx.x] = lds[0];
}

__global__ __launch_bounds__(256) void scan_p2(int* __restrict__ bsum, int nb) {
    __shared__ int lds[256];
    int t = threadIdx.x;
    int v = (t < nb) ? bsum[t] : 0;
    lds[t] = v;
    __syncthreads();
    for (int o = 1; o < 256; o <<= 1) {
        int tmp = 0;
        if (t >= o) tmp = lds[t - o];
        __syncthreads();
        lds[t] += tmp;
        __syncthreads();
    }
    if (t < nb) bsum[t] = lds[t] - v;  // exclusive
}

__global__ __launch_bounds__(256) void scan_p3(const int* __restrict__ deg, int n,
                                               const int* __restrict__ bsum,
                                               int* __restrict__ cptr,
                                               int* __restrict__ cur) {
    __shared__ int lds[256];
    int t = threadIdx.x;
    int base = blockIdx.x * 1024 + t * 4;
    int v[4];
    int s = 0;
#pragma unroll
    for (int i = 0; i < 4; i++) {
        int idx = base + i;
        v[i] = (idx < n) ? deg[idx] : 0;
        s += v[i];
    }
    lds[t] = s;
    __syncthreads();
    for (int o = 1; o < 256; o <<= 1) {
        int tmp = 0;
        if (t >= o) tmp = lds[t - o];
        __syncthreads();
        lds[t] += tmp;
        __syncthreads();
    }
    int off = bsum[blockIdx.x] + (lds[t] - s);
#pragma unroll
    for (int i = 0; i < 4; i++) {
        int idx = base + i;
        if (idx < n) {
            cptr[idx] = off;
            cur[idx] = off;
            off += v[i];
            if (idx == n - 1) cptr[n] = off;
        }
    }
}

// ---------------- pass 2: per-XCD counting-sort scatter from staged stream ------
// Team k (blockIdx&7 -> XCD k) reads ONLY its own staged chunk (~1.8MB stream)
// and scatters into its meta chunk (~850KB) + cur chunk (~50KB): total working
// set < 4MB L2, so meta lines stay resident until fully written (one writeback).
__global__ __launch_bounds__(256) void fill2_k(const unsigned long long* __restrict__ stg,
                                               int cap, const int* __restrict__ scnt,
                                               int N, int* __restrict__ cur,
                                               int* __restrict__ meta) {
    int k = blockIdx.x & 7;
    int team = blockIdx.x >> 3;
    int nteams = gridDim.x >> 3;
    int cnt = min(scnt[k], cap);
    const unsigned long long* src = stg + (size_t)k * cap;
    for (int i = team * 256 + threadIdx.x; i < cnt; i += nteams * 256) {
        unsigned long long v = src[i];
        int d = (int)(v >> 32);
        int s = (int)(v & 0xffffffffull);
        int p = atomicAdd(&cur[d], 1);
        meta[p] = s;
    }
    // self-loops for this chunk
    int chunk = (N + 7) >> 3;
    int dlo = k * chunk, dhi = min(N, dlo + chunk);
    for (int d = dlo + team * 256 + threadIdx.x; d < dhi; d += nteams * 256) {
        int p = atomicAdd(&cur[d], 1);
        meta[p] = d;
    }
}

// ---------------- f16 MFMA GEMM: C[n][DOUT] = (half)(dinv[r] * A[n][128] @ W) ------
template <typename AT, int DOUT>
__global__ __launch_bounds__(256) void gemm_mfma(const AT* __restrict__ A,
                                                 const __half* __restrict__ Wt,
                                                 const float* __restrict__ dinv,
                                                 __half* __restrict__ C, int n) {
    constexpr int CT = DOUT / 16;  // col tiles: 8 or 4
    constexpr int WP = 136;        // padded LDS stride (halves)
    __shared__ _Float16 ldsW[DOUT * WP];
    int tid = threadIdx.x;
    int lane = tid & 63;
    int wid = tid >> 6;
    for (int i = tid; i < DOUT * 16; i += 256) {
        int nrow = i >> 4;
        int kc = (i & 15) * 8;
        *(half8*)(&ldsW[nrow * WP + kc]) =
            *(const half8*)((const _Float16*)Wt + nrow * 128 + kc);
    }
    __syncthreads();
    int rwb = blockIdx.x * 128 + wid * 32;
    int m = lane & 15;
    int quad = lane >> 4;
    floatx4 acc[2][CT];
#pragma unroll
    for (int t = 0; t < 2; t++)
#pragma unroll
        for (int c = 0; c < CT; c++) acc[t][c] = (floatx4){0.f, 0.f, 0.f, 0.f};

#pragma unroll
    for (int kq = 0; kq < 4; kq++) {
        int k0 = kq * 32 + quad * 8;
        half8 afr[2];
#pragma unroll
        for (int t = 0; t < 2; t++) {
            int r = rwb + t * 16 + m;
            r = r < n ? r : n - 1;  // clamp (results unused for OOB rows)
            const AT* ap = A + (size_t)r * 128 + k0;
            if constexpr (sizeof(AT) == 2) {
                afr[t] = *(const half8*)ap;
            } else {
                float4 f0 = *(const float4*)ap;
                float4 f1 = *(const float4*)(ap + 4);
                half8 h;
                h[0] = (_Float16)f0.x; h[1] = (_Float16)f0.y;
                h[2] = (_Float16)f0.z; h[3] = (_Float16)f0.w;
                h[4] = (_Float16)f1.x; h[5] = (_Float16)f1.y;
                h[6] = (_Float16)f1.z; h[7] = (_Float16)f1.w;
                afr[t] = h;
            }
        }
#pragma unroll
        for (int c = 0; c < CT; c++) {
            half8 bfr = *(const half8*)(&ldsW[(c * 16 + m) * WP + k0]);
#pragma unroll
            for (int t = 0; t < 2; t++)
                acc[t][c] =
                    __builtin_amdgcn_mfma_f32_16x16x32_f16(afr[t], bfr, acc[t][c], 0, 0, 0);
        }
    }
#pragma unroll
    for (int t = 0; t < 2; t++) {
#pragma unroll
        for (int reg = 0; reg < 4; reg++) {
            int r = rwb + t * 16 + quad * 4 + reg;
            if (r < n) {
                float dv = dinv[r];
#pragma unroll
                for (int c = 0; c < CT; c++)
                    C[(size_t)r * DOUT + c * 16 + m] = __float2half(acc[t][c][reg] * dv);
            }
        }
    }
}

// ---------------- gather-aggregate: out[d] = dinv[d] * sum xw[src] + bias ----------
template <int D, bool RELU, typename OT>
__global__ __launch_bounds__(256) void aggregate_k(const __half* __restrict__ xw,
                                                   const int* __restrict__ ptr,
                                                   const int* __restrict__ meta,
                                                   const float* __restrict__ bias,
                                                   const float* __restrict__ dinv,
                                                   OT* __restrict__ out, int n) {
    constexpr int GS = D / 8;    // lanes per row (16 or 8)
    constexpr int EPW = 64 / GS; // edges per wave-load (4 or 8)
    __shared__ int smeta[4][64];
    int lane = threadIdx.x & 63;
    int wid = threadIdx.x >> 6;
    int node = blockIdx.x * 4 + wid;
    if (node >= n) return;
    int e0 = ptr[node], e1 = ptr[node + 1];
    float dv = dinv[node];
    int sub = lane / GS;   // edge sub-slot
    int cg = lane % GS;    // column group: cols [cg*8, cg*8+8)
    const _Float16* xp = (const _Float16*)xw + cg * 8;
    float acc[8];
#pragma unroll
    for (int i = 0; i < 8; i++) acc[i] = 0.f;

    for (int base = e0; base < e1; base += 64) {
        int cnt = min(e1 - base, 64);
        if (lane < cnt) smeta[wid][lane] = meta[base + lane];
        for (int j = 0; j < cnt; j += EPW) {
            int e = j + sub;
            bool valid = e < cnt;
            int s = smeta[wid][valid ? e : 0];
            half8 v = *(const half8*)(xp + (size_t)s * D);
            float msk = valid ? 1.f : 0.f;
#pragma unroll
            for (int i = 0; i < 8; i++) acc[i] = fmaf(msk, (float)v[i], acc[i]);
        }
    }
#pragma unroll
    for (int off = GS; off < 64; off <<= 1) {
#pragma unroll
        for (int i = 0; i < 8; i++) acc[i] += __shfl_xor(acc[i], off, 64);
    }
    if (lane < GS) {
        float4 bb0 = *(const float4*)(bias + cg * 8);
        float4 bb1 = *(const float4*)(bias + cg * 8 + 4);
        float r[8];
        r[0] = acc[0] * dv + bb0.x; r[1] = acc[1] * dv + bb0.y;
        r[2] = acc[2] * dv + bb0.z; r[3] = acc[3] * dv + bb0.w;
        r[4] = acc[4] * dv + bb1.x; r[5] = acc[5] * dv + bb1.y;
        r[6] = acc[6] * dv + bb1.z; r[7] = acc[7] * dv + bb1.w;
        if (RELU) {
#pragma unroll
            for (int i = 0; i < 8; i++) r[i] = fmaxf(r[i], 0.f);
        }
        if constexpr (sizeof(OT) == 2) {
            half8 h;
#pragma unroll
            for (int i = 0; i < 8; i++) h[i] = (_Float16)r[i];
            *(half8*)((_Float16*)out + (size_t)node * D + cg * 8) = h;
        } else {
            float* op = (float*)out + (size_t)node * D + cg * 8;
            *(float4*)op = make_float4(r[0], r[1], r[2], r[3]);
            *(float4*)(op + 4) = make_float4(r[4], r[5], r[6], r[7]);
        }
    }
}

extern "C" void kernel_launch(void* const* d_in, const int* in_sizes, int n_in,
                              void* d_out, int out_size, void* d_ws, size_t ws_size,
                              hipStream_t stream) {
    const float* x = (const float*)d_in[0];
    const int* ei = (const int*)d_in[1];
    const float* W1 = (const float*)d_in[2];
    const float* b1 = (const float*)d_in[3];
    const float* W2 = (const float*)d_in[4];
    const float* b2 = (const float*)d_in[5];
    const float* W3 = (const float*)d_in[6];
    const float* b3 = (const float*)d_in[7];
    float* out = (float*)d_out;
    int N = in_sizes[0] / 128;
    int E = in_sizes[1] / 2;
    const int* row = ei;
    const int* col = ei + E;
    int T = E + N;

    char* w = (char*)d_ws;
    size_t off = 0;
    auto alloc = [&](size_t bytes) -> void* {
        void* p = w + off;
        off = (off + bytes + 511) & ~(size_t)511;
        return p;
    };
    __half* bufH = (__half*)alloc((size_t)N * 128 * 2);   // xw (dinv-scaled, fp16)
    __half* bufA = (__half*)alloc((size_t)N * 128 * 2);   // hidden h (fp16 GEMM input)
    __half* Wt1 = (__half*)alloc(16384 * 2);
    __half* Wt2 = (__half*)alloc(16384 * 2);
    __half* Wt3 = (__half*)alloc(8192 * 2);
    int* deg = (int*)alloc((size_t)N * 4);
    float* dinv = (float*)alloc((size_t)N * 4);
    int* cptr = (int*)alloc((size_t)(N + 1) * 4);
    int* cur = (int*)alloc((size_t)N * 4);
    int* meta = (int*)alloc((size_t)T * 4);
    int* bsum = (int*)alloc(4096);
    int* scnt = (int*)alloc(64);

    // staging aliases bufH: dead until gemm1, which runs after fill2_k (stream order)
    int cap = (E >> 3) + (E >> 6) + 1024;  // E/8 + ~1.6% slack (~60 sigma for uniform dst)
    unsigned long long* stg = (unsigned long long*)bufH;  // 8*cap*8B = ~14.5MB <= 25.6MB

    int nb = (N + 1023) / 1024;
    wconv_k<<<160, 256, 0, stream>>>(W1, W2, W3, Wt1, Wt2, Wt3);
    deg_init_k<<<(N + 255) / 256, 256, 0, stream>>>(deg, N, scnt);
    part_k<<<2048, 256, 0, stream>>>(row, col, E, N, deg, stg, cap, scnt);
    dinv_k<<<(N + 255) / 256, 256, 0, stream>>>(deg, dinv, N);
    scan_p1<<<nb, 256, 0, stream>>>(deg, N, bsum);
    scan_p2<<<1, 256, 0, stream>>>(bsum, nb);
    scan_p3<<<nb, 256, 0, stream>>>(deg, N, bsum, cptr, cur);
    fill2_k<<<2048, 256, 0, stream>>>(stg, cap, scnt, N, cur, meta);

    int gb = (N + 127) / 128;
    int ab = (N + 3) / 4;
    gemm_mfma<float, 128><<<gb, 256, 0, stream>>>(x, Wt1, dinv, bufH, N);
    aggregate_k<128, true, __half><<<ab, 256, 0, stream>>>(bufH, cptr, meta, b1, dinv, bufA, N);
    gemm_mfma<__half, 128><<<gb, 256, 0, stream>>>(bufA, Wt2, dinv, bufH, N);
    aggregate_k<128, true, __half><<<ab, 256, 0, stream>>>(bufH, cptr, meta, b2, dinv, bufA, N);
    gemm_mfma<__half, 64><<<gb, 256, 0, stream>>>(bufA, Wt3, dinv, bufH, N);
    aggregate_k<64, false, float><<<ab, 256, 0, stream>>>(bufH, cptr, meta, b3, dinv, out, N);
}

// Round 3
// 489.496 us; speedup vs baseline: 1.0025x; 1.0025x over previous
//
#include <hip/hip_runtime.h>
#include <hip/hip_fp16.h>

typedef _Float16 half8 __attribute__((ext_vector_type(8)));
typedef float floatx4 __attribute__((ext_vector_type(4)));

#define PSLOTS 224     // LDS bucket slots per chunk (mean 128, sigma ~10.6 -> +9 sigma)
#define OVFCAP 65536   // overflow spill capacity (pairs)

// ---------------- degree init (+ zero padded cursors & overflow count) ----------
__global__ __launch_bounds__(256) void deg_init_k(int* __restrict__ deg, int n,
                                                  int* __restrict__ scnt,
                                                  int* __restrict__ ovfcnt) {
    int i = blockIdx.x * 256 + threadIdx.x;
    if (i < n) deg[i] = 1;  // self-loop
    if (blockIdx.x == 0 && threadIdx.x < 128) scnt[threadIdx.x] = 0;  // 8 x 64B-padded
    if (blockIdx.x == 0 && threadIdx.x == 128) *ovfcnt = 0;
}

__global__ __launch_bounds__(256) void dinv_k(const int* __restrict__ deg,
                                              float* __restrict__ dinv, int n) {
    int i = blockIdx.x * 256 + threadIdx.x;
    if (i < n) dinv[i] = rsqrtf((float)deg[i]);
}

// ---------------- weight convert + transpose: Wt[n][k] = (half)W[k][n] ----------
__global__ __launch_bounds__(256) void wconv_k(const float* __restrict__ W1,
                                               const float* __restrict__ W2,
                                               const float* __restrict__ W3,
                                               __half* __restrict__ Wt1,
                                               __half* __restrict__ Wt2,
                                               __half* __restrict__ Wt3) {
    int idx = blockIdx.x * 256 + threadIdx.x;
    if (idx < 16384) {
        int k = idx >> 7, nn = idx & 127;
        Wt1[nn * 128 + k] = __float2half(W1[idx]);
    } else if (idx < 32768) {
        int j = idx - 16384;
        int k = j >> 7, nn = j & 127;
        Wt2[nn * 128 + k] = __float2half(W2[j]);
    } else if (idx < 40960) {
        int j = idx - 32768;
        int k = j >> 6, nn = j & 63;
        Wt3[nn * 128 + k] = __float2half(W3[j]);
    }
}

// ---------------- pass 1: LDS-binned partition into 8 dst-chunk streams ---------
// One 1024-edge tile per block. Edges are ranked into 8 LDS buckets (per-edge LDS
// atomic -- R2 counters show LDS contention is negligible), the block claims ONE
// padded global cursor slot per chunk (12.5K total atomics over 8 independent
// lines, vs R2's 50K on a single line = the measured 100us serialization), then a
// flat cooperative write-out streams each bucket contiguously -> full-line
// coalesced stores (vs R2's scattered 8B stores = 63MB of 32B sector bursts).
// Also fuses the degree count. Chunk binning is float-approximate: bucket choice
// only affects XCD locality, never correctness (d travels inside the pair).
__global__ __launch_bounds__(256) void part_k(const int* __restrict__ row,
                                              const int* __restrict__ col, int E, int N,
                                              int* __restrict__ deg,
                                              unsigned long long* __restrict__ stg,
                                              int cap, int* __restrict__ scnt,
                                              unsigned long long* __restrict__ ovf,
                                              int* __restrict__ ovfcnt) {
    __shared__ unsigned long long bkt[8][PSLOTS];
    __shared__ int lcnt[8], lbase[8], lpref[9];
    int tid = threadIdx.x;
    if (tid < 8) lcnt[tid] = 0;
    __syncthreads();

    int i0 = blockIdx.x * 1024 + tid * 4;
    float inv = 8.0f / (float)N;
    int sv[4], dv[4];
    int nv = 0;
    if (i0 + 3 < E && (E & 3) == 0) {  // col = ei+E stays 16B-aligned iff E%4==0
        int4 r4 = *(const int4*)(row + i0);
        int4 c4 = *(const int4*)(col + i0);
        sv[0] = r4.x; sv[1] = r4.y; sv[2] = r4.z; sv[3] = r4.w;
        dv[0] = c4.x; dv[1] = c4.y; dv[2] = c4.z; dv[3] = c4.w;
        nv = 4;
    } else {
#pragma unroll
        for (int j = 0; j < 4; j++) {
            if (i0 + j < E) { sv[nv] = row[i0 + j]; dv[nv] = col[i0 + j]; nv++; }
        }
    }
#pragma unroll 4
    for (int j = 0; j < nv; j++) {
        int d = dv[j], s = sv[j];
        atomicAdd(&deg[d], 1);
        int c = min(7, (int)((float)d * inv));
        int r = atomicAdd(&lcnt[c], 1);
        unsigned long long pair = ((unsigned long long)(unsigned)d << 32) | (unsigned)s;
        if (r < PSLOTS) {
            bkt[c][r] = pair;
        } else {  // ~1e-15 probability; correctness guard
            int o = atomicAdd(ovfcnt, 1);
            if (o < OVFCAP) ovf[o] = pair;
        }
    }
    __syncthreads();
    if (tid < 8) {
        int cc = min(lcnt[tid], PSLOTS);
        lcnt[tid] = cc;
        lbase[tid] = atomicAdd(&scnt[tid * 16], cc);  // 64B-padded cursors
    }
    __syncthreads();
    if (tid == 0) {
        int a = 0;
#pragma unroll
        for (int c = 0; c < 8; c++) { lpref[c] = a; a += lcnt[c]; }
        lpref[8] = a;
    }
    __syncthreads();
    int total = lpref[8];
    for (int f = tid; f < total; f += 256) {
        int c = 0;
        while (c < 7 && f >= lpref[c + 1]) c++;
        int slot = f - lpref[c];
        int gidx = lbase[c] + slot;
        if (gidx < cap) {
            stg[(size_t)c * cap + gidx] = bkt[c][slot];
        } else {
            int o = atomicAdd(ovfcnt, 1);
            if (o < OVFCAP) ovf[o] = bkt[c][slot];
        }
    }
}

// ---------------- 3-phase exclusive scan of deg -> col_ptr ----------------
__global__ __launch_bounds__(256) void scan_p1(const int* __restrict__ deg, int n,
                                               int* __restrict__ bsum) {
    __shared__ int lds[256];
    int t = threadIdx.x;
    int base = blockIdx.x * 1024 + t * 4;
    int s = 0;
#pragma unroll
    for (int i = 0; i < 4; i++) {
        int idx = base + i;
        if (idx < n) s += deg[idx];
    }
    lds[t] = s;
    __syncthreads();
    for (int o = 128; o > 0; o >>= 1) {
        if (t < o) lds[t] += lds[t + o];
        __syncthreads();
    }
    if (t == 0) bsum[blockIdx.x] = lds[0];
}

__global__ __launch_bounds__(256) void scan_p2(int* __restrict__ bsum, int nb) {
    __shared__ int lds[256];
    int t = threadIdx.x;
    int v = (t < nb) ? bsum[t] : 0;
    lds[t] = v;
    __syncthreads();
    for (int o = 1; o < 256; o <<= 1) {
        int tmp = 0;
        if (t >= o) tmp = lds[t - o];
        __syncthreads();
        lds[t] += tmp;
        __syncthreads();
    }
    if (t < nb) bsum[t] = lds[t] - v;  // exclusive
}

__global__ __launch_bounds__(256) void scan_p3(const int* __restrict__ deg, int n,
                                               const int* __restrict__ bsum,
                                               int* __restrict__ cptr,
                                               int* __restrict__ cur) {
    __shared__ int lds[256];
    int t = threadIdx.x;
    int base = blockIdx.x * 1024 + t * 4;
    int v[4];
    int s = 0;
#pragma unroll
    for (int i = 0; i < 4; i++) {
        int idx = base + i;
        v[i] = (idx < n) ? deg[idx] : 0;
        s += v[i];
    }
    lds[t] = s;
    __syncthreads();
    for (int o = 1; o < 256; o <<= 1) {
        int tmp = 0;
        if (t >= o) tmp = lds[t - o];
        __syncthreads();
        lds[t] += tmp;
        __syncthreads();
    }
    int off = bsum[blockIdx.x] + (lds[t] - s);
#pragma unroll
    for (int i = 0; i < 4; i++) {
        int idx = base + i;
        if (idx < n) {
            cptr[idx] = off;
            cur[idx] = off;
            off += v[i];
            if (idx == n - 1) cptr[n] = off;
        }
    }
}

// ---------------- pass 2: per-XCD counting-sort scatter from staged stream ------
// Team k (blockIdx&7 -> XCD k) reads ONLY its own staged chunk (~1.9MB stream,
// read once collectively) and scatters into its meta chunk (~850KB) + cur chunk
// (~50KB): working set < 4MB L2 -> meta lines stay resident until fully written.
__global__ __launch_bounds__(256) void fill2_k(const unsigned long long* __restrict__ stg,
                                               int cap, const int* __restrict__ scnt,
                                               const unsigned long long* __restrict__ ovf,
                                               const int* __restrict__ ovfcnt,
                                               int N, int* __restrict__ cur,
                                               int* __restrict__ meta) {
    int k = blockIdx.x & 7;
    int team = blockIdx.x >> 3;
    int nteams = gridDim.x >> 3;
    int cnt = min(scnt[k * 16], cap);
    const unsigned long long* src = stg + (size_t)k * cap;
    for (int i = team * 256 + threadIdx.x; i < cnt; i += nteams * 256) {
        unsigned long long v = src[i];
        int d = (int)(v >> 32);
        int s = (int)(v & 0xffffffffull);
        int p = atomicAdd(&cur[d], 1);
        meta[p] = s;
    }
    // self-loops for this chunk (exact ranges; independent of approx binning)
    int chunk = (N + 7) >> 3;
    int dlo = k * chunk, dhi = min(N, dlo + chunk);
    for (int d = dlo + team * 256 + threadIdx.x; d < dhi; d += nteams * 256) {
        int p = atomicAdd(&cur[d], 1);
        meta[p] = d;
    }
    // overflow spills (normally zero)
    int oc = min(*ovfcnt, OVFCAP);
    for (int i = team * 256 + threadIdx.x; i < oc; i += nteams * 256) {
        unsigned long long v = ovf[i];
        int d = (int)(v >> 32);
        int s = (int)(v & 0xffffffffull);
        if (d >= dlo && d < dhi) {
            int p = atomicAdd(&cur[d], 1);
            meta[p] = s;
        }
    }
}

// ---------------- f16 MFMA GEMM: C[n][DOUT] = (half)(dinv[r] * A[n][128] @ W) ------
template <typename AT, int DOUT>
__global__ __launch_bounds__(256) void gemm_mfma(const AT* __restrict__ A,
                                                 const __half* __restrict__ Wt,
                                                 const float* __restrict__ dinv,
                                                 __half* __restrict__ C, int n) {
    constexpr int CT = DOUT / 16;  // col tiles: 8 or 4
    constexpr int WP = 136;        // padded LDS stride (halves)
    __shared__ _Float16 ldsW[DOUT * WP];
    int tid = threadIdx.x;
    int lane = tid & 63;
    int wid = tid >> 6;
    for (int i = tid; i < DOUT * 16; i += 256) {
        int nrow = i >> 4;
        int kc = (i & 15) * 8;
        *(half8*)(&ldsW[nrow * WP + kc]) =
            *(const half8*)((const _Float16*)Wt + nrow * 128 + kc);
    }
    __syncthreads();
    int rwb = blockIdx.x * 128 + wid * 32;
    int m = lane & 15;
    int quad = lane >> 4;
    floatx4 acc[2][CT];
#pragma unroll
    for (int t = 0; t < 2; t++)
#pragma unroll
        for (int c = 0; c < CT; c++) acc[t][c] = (floatx4){0.f, 0.f, 0.f, 0.f};

#pragma unroll
    for (int kq = 0; kq < 4; kq++) {
        int k0 = kq * 32 + quad * 8;
        half8 afr[2];
#pragma unroll
        for (int t = 0; t < 2; t++) {
            int r = rwb + t * 16 + m;
            r = r < n ? r : n - 1;  // clamp (results unused for OOB rows)
            const AT* ap = A + (size_t)r * 128 + k0;
            if constexpr (sizeof(AT) == 2) {
                afr[t] = *(const half8*)ap;
            } else {
                float4 f0 = *(const float4*)ap;
                float4 f1 = *(const float4*)(ap + 4);
                half8 h;
                h[0] = (_Float16)f0.x; h[1] = (_Float16)f0.y;
                h[2] = (_Float16)f0.z; h[3] = (_Float16)f0.w;
                h[4] = (_Float16)f1.x; h[5] = (_Float16)f1.y;
                h[6] = (_Float16)f1.z; h[7] = (_Float16)f1.w;
                afr[t] = h;
            }
        }
#pragma unroll
        for (int c = 0; c < CT; c++) {
            half8 bfr = *(const half8*)(&ldsW[(c * 16 + m) * WP + k0]);
#pragma unroll
            for (int t = 0; t < 2; t++)
                acc[t][c] =
                    __builtin_amdgcn_mfma_f32_16x16x32_f16(afr[t], bfr, acc[t][c], 0, 0, 0);
        }
    }
#pragma unroll
    for (int t = 0; t < 2; t++) {
#pragma unroll
        for (int reg = 0; reg < 4; reg++) {
            int r = rwb + t * 16 + quad * 4 + reg;
            if (r < n) {
                float dv = dinv[r];
#pragma unroll
                for (int c = 0; c < CT; c++)
                    C[(size_t)r * DOUT + c * 16 + m] = __float2half(acc[t][c][reg] * dv);
            }
        }
    }
}

// ---------------- gather-aggregate: out[d] = dinv[d] * sum xw[src] + bias ----------
template <int D, bool RELU, typename OT>
__global__ __launch_bounds__(256) void aggregate_k(const __half* __restrict__ xw,
                                                   const int* __restrict__ ptr,
                                                   const int* __restrict__ meta,
                                                   const float* __restrict__ bias,
                                                   const float* __restrict__ dinv,
                                                   OT* __restrict__ out, int n) {
    constexpr int GS = D / 8;    // lanes per row (16 or 8)
    constexpr int EPW = 64 / GS; // edges per wave-load (4 or 8)
    __shared__ int smeta[4][64];
    int lane = threadIdx.x & 63;
    int wid = threadIdx.x >> 6;
    int node = blockIdx.x * 4 + wid;
    if (node >= n) return;
    int e0 = ptr[node], e1 = ptr[node + 1];
    float dv = dinv[node];
    int sub = lane / GS;   // edge sub-slot
    int cg = lane % GS;    // column group: cols [cg*8, cg*8+8)
    const _Float16* xp = (const _Float16*)xw + cg * 8;
    float acc[8];
#pragma unroll
    for (int i = 0; i < 8; i++) acc[i] = 0.f;

    for (int base = e0; base < e1; base += 64) {
        int cnt = min(e1 - base, 64);
        if (lane < cnt) smeta[wid][lane] = meta[base + lane];
        for (int j = 0; j < cnt; j += EPW) {
            int e = j + sub;
            bool valid = e < cnt;
            int s = smeta[wid][valid ? e : 0];
            half8 v = *(const half8*)(xp + (size_t)s * D);
            float msk = valid ? 1.f : 0.f;
#pragma unroll
            for (int i = 0; i < 8; i++) acc[i] = fmaf(msk, (float)v[i], acc[i]);
        }
    }
#pragma unroll
    for (int off = GS; off < 64; off <<= 1) {
#pragma unroll
        for (int i = 0; i < 8; i++) acc[i] += __shfl_xor(acc[i], off, 64);
    }
    if (lane < GS) {
        float4 bb0 = *(const float4*)(bias + cg * 8);
        float4 bb1 = *(const float4*)(bias + cg * 8 + 4);
        float r[8];
        r[0] = acc[0] * dv + bb0.x; r[1] = acc[1] * dv + bb0.y;
        r[2] = acc[2] * dv + bb0.z; r[3] = acc[3] * dv + bb0.w;
        r[4] = acc[4] * dv + bb1.x; r[5] = acc[5] * dv + bb1.y;
        r[6] = acc[6] * dv + bb1.z; r[7] = acc[7] * dv + bb1.w;
        if (RELU) {
#pragma unroll
            for (int i = 0; i < 8; i++) r[i] = fmaxf(r[i], 0.f);
        }
        if constexpr (sizeof(OT) == 2) {
            half8 h;
#pragma unroll
            for (int i = 0; i < 8; i++) h[i] = (_Float16)r[i];
            *(half8*)((_Float16*)out + (size_t)node * D + cg * 8) = h;
        } else {
            float* op = (float*)out + (size_t)node * D + cg * 8;
            *(float4*)op = make_float4(r[0], r[1], r[2], r[3]);
            *(float4*)(op + 4) = make_float4(r[4], r[5], r[6], r[7]);
        }
    }
}

extern "C" void kernel_launch(void* const* d_in, const int* in_sizes, int n_in,
                              void* d_out, int out_size, void* d_ws, size_t ws_size,
                              hipStream_t stream) {
    const float* x = (const float*)d_in[0];
    const int* ei = (const int*)d_in[1];
    const float* W1 = (const float*)d_in[2];
    const float* b1 = (const float*)d_in[3];
    const float* W2 = (const float*)d_in[4];
    const float* b2 = (const float*)d_in[5];
    const float* W3 = (const float*)d_in[6];
    const float* b3 = (const float*)d_in[7];
    float* out = (float*)d_out;
    int N = in_sizes[0] / 128;
    int E = in_sizes[1] / 2;
    const int* row = ei;
    const int* col = ei + E;
    int T = E + N;

    char* w = (char*)d_ws;
    size_t off = 0;
    auto alloc = [&](size_t bytes) -> void* {
        void* p = w + off;
        off = (off + bytes + 511) & ~(size_t)511;
        return p;
    };
    __half* bufH = (__half*)alloc((size_t)N * 128 * 2);   // xw (dinv-scaled, fp16)
    __half* bufA = (__half*)alloc((size_t)N * 128 * 2);   // hidden h (fp16 GEMM input)
    __half* Wt1 = (__half*)alloc(16384 * 2);
    __half* Wt2 = (__half*)alloc(16384 * 2);
    __half* Wt3 = (__half*)alloc(8192 * 2);
    int* deg = (int*)alloc((size_t)N * 4);
    float* dinv = (float*)alloc((size_t)N * 4);
    int* cptr = (int*)alloc((size_t)(N + 1) * 4);
    int* cur = (int*)alloc((size_t)N * 4);
    int* meta = (int*)alloc((size_t)T * 4);
    int* bsum = (int*)alloc(4096);
    int* scnt = (int*)alloc(128 * 4);   // 8 cursors, 64B-padded
    int* ovfcnt = (int*)alloc(64);
    unsigned long long* ovf = (unsigned long long*)alloc((size_t)OVFCAP * 8);

    // staging aliases bufH: dead until gemm1, which runs after fill2_k (stream order)
    int cap = (E >> 3) + (E >> 6) + 1024;  // E/8 + ~60 sigma slack for uniform dst
    unsigned long long* stg = (unsigned long long*)bufH;  // 8*cap*8B ~= 14.5MB <= 25.6MB

    int nb = (N + 1023) / 1024;
    int pb = (E + 1023) / 1024;
    wconv_k<<<160, 256, 0, stream>>>(W1, W2, W3, Wt1, Wt2, Wt3);
    deg_init_k<<<(N + 255) / 256, 256, 0, stream>>>(deg, N, scnt, ovfcnt);
    part_k<<<pb, 256, 0, stream>>>(row, col, E, N, deg, stg, cap, scnt, ovf, ovfcnt);
    dinv_k<<<(N + 255) / 256, 256, 0, stream>>>(deg, dinv, N);
    scan_p1<<<nb, 256, 0, stream>>>(deg, N, bsum);
    scan_p2<<<1, 256, 0, stream>>>(bsum, nb);
    scan_p3<<<nb, 256, 0, stream>>>(deg, N, bsum, cptr, cur);
    fill2_k<<<2048, 256, 0, stream>>>(stg, cap, scnt, ovf, ovfcnt, N, cur, meta);

    int gb = (N + 127) / 128;
    int ab = (N + 3) / 4;
    gemm_mfma<float, 128><<<gb, 256, 0, stream>>>(x, Wt1, dinv, bufH, N);
    aggregate_k<128, true, __half><<<ab, 256, 0, stream>>>(bufH, cptr, meta, b1, dinv, bufA, N);
    gemm_mfma<__half, 128><<<gb, 256, 0, stream>>>(bufA, Wt2, dinv, bufH, N);
    aggregate_k<128, true, __half><<<ab, 256, 0, stream>>>(bufH, cptr, meta, b2, dinv, bufA, N);
    gemm_mfma<__half, 64><<<gb, 256, 0, stream>>>(bufA, Wt3, dinv, bufH, N);
    aggregate_k<64, false, float><<<ab, 256, 0, stream>>>(bufH, cptr, meta, b3, dinv, out, N);
}

// Round 4
// 407.050 us; speedup vs baseline: 1.2055x; 1.2025x over previous
//
#include <hip/hip_runtime.h>
#include <hip/hip_fp16.h>

typedef _Float16 half8 __attribute__((ext_vector_type(8)));
typedef float floatx4 __attribute__((ext_vector_type(4)));

#define NCH 128      // dst chunks (one fill/degcnt block per chunk)
#define TILE 2048    // edges per part_k block
#define CSLOT 48     // slots per (chunk,block) cell: mean 16, +8 sigma
#define MAXNB 1024   // max part_k blocks supported (E <= 2M)
#define MAXCH 1024   // max nodes per chunk supported (N <= 128K)
#define OVFCAP 65536 // overflow spill capacity (pairs)

// ---------------- weight convert + transpose: Wt[n][k] = (half)W[k][n] ----------
// (also zeroes the overflow counter: idx 40960)
__global__ __launch_bounds__(256) void wconv_k(const float* __restrict__ W1,
                                               const float* __restrict__ W2,
                                               const float* __restrict__ W3,
                                               __half* __restrict__ Wt1,
                                               __half* __restrict__ Wt2,
                                               __half* __restrict__ Wt3,
                                               int* __restrict__ ovfcnt) {
    int idx = blockIdx.x * 256 + threadIdx.x;
    if (idx < 16384) {
        int k = idx >> 7, nn = idx & 127;
        Wt1[nn * 128 + k] = __float2half(W1[idx]);
    } else if (idx < 32768) {
        int j = idx - 16384;
        int k = j >> 7, nn = j & 127;
        Wt2[nn * 128 + k] = __float2half(W2[j]);
    } else if (idx < 40960) {
        int j = idx - 32768;
        int k = j >> 6, nn = j & 63;
        Wt3[nn * 128 + k] = __float2half(W3[j]);
    } else if (idx == 40960) {
        *ovfcnt = 0;
    }
}

// ---------------- pass 1: deterministic-cell partition (NO global atomics) -------
// Each block owns a 2048-edge tile and a fixed 48-slot cell per chunk:
// stg_[d|s][((c*NB)+b)*CSLOT + slot]. Per-edge work is one LDS atomic (rank) and
// the write-out; the per-(chunk,block) counts go to cnts[c*NB+b] with plain
// stores. R2==R3 (99us) proved per-edge global atomicAdd(deg) was the entire
// cost (1.6M scattered memory-side atomics = 51MB of WRITE sectors); deg
// counting moves to degcnt_k (LDS histogram), so this kernel issues ZERO
// per-edge global atomics.
__global__ __launch_bounds__(256) void part_k(const int* __restrict__ row,
                                              const int* __restrict__ col, int E,
                                              int chunk, int NB,
                                              int* __restrict__ stg_d,
                                              int* __restrict__ stg_s,
                                              int* __restrict__ cnts,
                                              unsigned long long* __restrict__ ovf,
                                              int* __restrict__ ovfcnt) {
    __shared__ int bd[NCH][CSLOT];
    __shared__ int bs[NCH][CSLOT];
    __shared__ int lcnt[NCH];
    __shared__ int lpref[NCH + 1];
    int tid = threadIdx.x;
    int b = blockIdx.x;
    for (int i = tid; i < NCH; i += 256) lcnt[i] = 0;
    __syncthreads();

    int i0 = b * TILE + tid * 8;
    int sv[8], dv[8];
    int nv = 0;
    if (i0 + 7 < E && (E & 3) == 0) {  // col = ei+E stays 16B-aligned iff E%4==0
        int4 r0 = *(const int4*)(row + i0);
        int4 r1 = *(const int4*)(row + i0 + 4);
        int4 c0 = *(const int4*)(col + i0);
        int4 c1 = *(const int4*)(col + i0 + 4);
        sv[0] = r0.x; sv[1] = r0.y; sv[2] = r0.z; sv[3] = r0.w;
        sv[4] = r1.x; sv[5] = r1.y; sv[6] = r1.z; sv[7] = r1.w;
        dv[0] = c0.x; dv[1] = c0.y; dv[2] = c0.z; dv[3] = c0.w;
        dv[4] = c1.x; dv[5] = c1.y; dv[6] = c1.z; dv[7] = c1.w;
        nv = 8;
    } else {
#pragma unroll
        for (int j = 0; j < 8; j++) {
            if (i0 + j < E) { sv[nv] = row[i0 + j]; dv[nv] = col[i0 + j]; nv++; }
        }
    }
#pragma unroll 8
    for (int j = 0; j < nv; j++) {
        int d = dv[j], s = sv[j];
        int c = d / chunk;  // exact integer binning (must match fill/degcnt ranges)
        int r = atomicAdd(&lcnt[c], 1);
        if (r < CSLOT) {
            bd[c][r] = d;
            bs[c][r] = s;
        } else {  // ~1e-17/cell; correctness guard
            int o = atomicAdd(ovfcnt, 1);
            if (o < OVFCAP)
                ovf[o] = ((unsigned long long)(unsigned)d << 32) | (unsigned)s;
        }
    }
    __syncthreads();
    if (tid == 0) {
        int a = 0;
#pragma unroll
        for (int c = 0; c < NCH; c++) {
            lpref[c] = a;
            a += min(lcnt[c], CSLOT);
        }
        lpref[NCH] = a;
    }
    __syncthreads();
    for (int c = tid; c < NCH; c += 256) cnts[(size_t)c * NB + b] = min(lcnt[c], CSLOT);
    int total = lpref[NCH];
    for (int f = tid; f < total; f += 256) {
        int lo = 0, hi = NCH;  // binary search: largest c with lpref[c] <= f
        while (hi - lo > 1) {
            int mid = (lo + hi) >> 1;
            if (lpref[mid] <= f) lo = mid; else hi = mid;
        }
        int slot = f - lpref[lo];
        size_t cell = ((size_t)lo * NB + b) * CSLOT;
        stg_d[cell + slot] = bd[lo][slot];
        stg_s[cell + slot] = bs[lo][slot];
    }
}

// ---------------- pass 2a: per-chunk degree histogram (LDS only) -----------------
// One block per chunk. hist starts at 1 (self-loop). Writes deg AND dinv with
// plain coalesced stores -- replaces 1.6M global atomics + deg_init + dinv_k.
__global__ __launch_bounds__(256) void degcnt_k(const int* __restrict__ stg_d,
                                                const int* __restrict__ cnts, int NB,
                                                int N, int chunk,
                                                const unsigned long long* __restrict__ ovf,
                                                const int* __restrict__ ovfcnt,
                                                int* __restrict__ deg,
                                                float* __restrict__ dinv) {
    __shared__ int hist[MAXCH];
    __shared__ int lc[MAXNB];
    int c = blockIdx.x, tid = threadIdx.x;
    int dlo = c * chunk;
    int dhi = min(N, dlo + chunk);
    int csz = dhi - dlo;
    if (csz <= 0) return;
    for (int i = tid; i < csz; i += 256) hist[i] = 1;  // self-loop
    for (int i = tid; i < NB; i += 256) lc[i] = cnts[(size_t)c * NB + i];
    __syncthreads();
    // 16 lanes per cell, 16 cells in flight per 256-thread step
    for (int b0 = tid >> 4; b0 < NB; b0 += 16) {
        int cnt = lc[b0];
        size_t base = ((size_t)c * NB + b0) * CSLOT;
        for (int slot = tid & 15; slot < cnt; slot += 16) {
            int d = stg_d[base + slot];
            atomicAdd(&hist[d - dlo], 1);
        }
    }
    __syncthreads();
    int oc = min(*ovfcnt, OVFCAP);
    for (int i = tid; i < oc; i += 256) {
        int d = (int)(ovf[i] >> 32);
        if (d >= dlo && d < dhi) atomicAdd(&hist[d - dlo], 1);
    }
    __syncthreads();
    for (int i = tid; i < csz; i += 256) {
        int dg = hist[i];
        deg[dlo + i] = dg;
        dinv[dlo + i] = rsqrtf((float)dg);
    }
}

// ---------------- 3-phase exclusive scan of deg -> col_ptr ----------------
__global__ __launch_bounds__(256) void scan_p1(const int* __restrict__ deg, int n,
                                               int* __restrict__ bsum) {
    __shared__ int lds[256];
    int t = threadIdx.x;
    int base = blockIdx.x * 1024 + t * 4;
    int s = 0;
#pragma unroll
    for (int i = 0; i < 4; i++) {
        int idx = base + i;
        if (idx < n) s += deg[idx];
    }
    lds[t] = s;
    __syncthreads();
    for (int o = 128; o > 0; o >>= 1) {
        if (t < o) lds[t] += lds[t + o];
        __syncthreads();
    }
    if (t == 0) bsum[blockIdx.x] = lds[0];
}

__global__ __launch_bounds__(256) void scan_p2(int* __restrict__ bsum, int nb) {
    __shared__ int lds[256];
    int t = threadIdx.x;
    int v = (t < nb) ? bsum[t] : 0;
    lds[t] = v;
    __syncthreads();
    for (int o = 1; o < 256; o <<= 1) {
        int tmp = 0;
        if (t >= o) tmp = lds[t - o];
        __syncthreads();
        lds[t] += tmp;
        __syncthreads();
    }
    if (t < nb) bsum[t] = lds[t] - v;  // exclusive
}

__global__ __launch_bounds__(256) void scan_p3(const int* __restrict__ deg, int n,
                                               const int* __restrict__ bsum,
                                               int* __restrict__ cptr) {
    __shared__ int lds[256];
    int t = threadIdx.x;
    int base = blockIdx.x * 1024 + t * 4;
    int v[4];
    int s = 0;
#pragma unroll
    for (int i = 0; i < 4; i++) {
        int idx = base + i;
        v[i] = (idx < n) ? deg[idx] : 0;
        s += v[i];
    }
    lds[t] = s;
    __syncthreads();
    for (int o = 1; o < 256; o <<= 1) {
        int tmp = 0;
        if (t >= o) tmp = lds[t - o];
        __syncthreads();
        lds[t] += tmp;
        __syncthreads();
    }
    int off = bsum[blockIdx.x] + (lds[t] - s);
#pragma unroll
    for (int i = 0; i < 4; i++) {
        int idx = base + i;
        if (idx < n) {
            cptr[idx] = off;
            off += v[i];
            if (idx == n - 1) cptr[n] = off;
        }
    }
}

// ---------------- pass 2b: per-chunk scatter with LDS cursors (NO global atomics)
// One block per chunk: cptr slice -> LDS cursor array; each staged pair gets its
// meta position from an LDS atomicAdd. meta stores land in the chunk's ~53KB
// window (L2-resident). Self-loops + overflow drained in-chunk.
__global__ __launch_bounds__(256) void fill3_k(const int* __restrict__ stg_d,
                                               const int* __restrict__ stg_s,
                                               const int* __restrict__ cnts, int NB,
                                               const int* __restrict__ cptr,
                                               int N, int chunk,
                                               const unsigned long long* __restrict__ ovf,
                                               const int* __restrict__ ovfcnt,
                                               int* __restrict__ meta) {
    __shared__ int cur[MAXCH];
    __shared__ int lc[MAXNB];
    int c = blockIdx.x, tid = threadIdx.x;
    int dlo = c * chunk;
    int dhi = min(N, dlo + chunk);
    int csz = dhi - dlo;
    if (csz <= 0) return;
    for (int i = tid; i < csz; i += 256) cur[i] = cptr[dlo + i];
    for (int i = tid; i < NB; i += 256) lc[i] = cnts[(size_t)c * NB + i];
    __syncthreads();
    for (int b0 = tid >> 4; b0 < NB; b0 += 16) {
        int cnt = lc[b0];
        size_t base = ((size_t)c * NB + b0) * CSLOT;
        for (int slot = tid & 15; slot < cnt; slot += 16) {
            int d = stg_d[base + slot];
            int s = stg_s[base + slot];
            int p = atomicAdd(&cur[d - dlo], 1);
            meta[p] = s;
        }
    }
    // self-loops
    for (int i = tid; i < csz; i += 256) {
        int p = atomicAdd(&cur[i], 1);
        meta[p] = dlo + i;
    }
    // overflow spills (normally zero)
    int oc = min(*ovfcnt, OVFCAP);
    for (int i = tid; i < oc; i += 256) {
        unsigned long long v = ovf[i];
        int d = (int)(v >> 32);
        if (d >= dlo && d < dhi) {
            int p = atomicAdd(&cur[d - dlo], 1);
            meta[p] = (int)(v & 0xffffffffull);
        }
    }
}

// ---------------- f16 MFMA GEMM: C[n][DOUT] = (half)(dinv[r] * A[n][128] @ W) ------
template <typename AT, int DOUT>
__global__ __launch_bounds__(256) void gemm_mfma(const AT* __restrict__ A,
                                                 const __half* __restrict__ Wt,
                                                 const float* __restrict__ dinv,
                                                 __half* __restrict__ C, int n) {
    constexpr int CT = DOUT / 16;  // col tiles: 8 or 4
    constexpr int WP = 136;        // padded LDS stride (halves)
    __shared__ _Float16 ldsW[DOUT * WP];
    int tid = threadIdx.x;
    int lane = tid & 63;
    int wid = tid >> 6;
    for (int i = tid; i < DOUT * 16; i += 256) {
        int nrow = i >> 4;
        int kc = (i & 15) * 8;
        *(half8*)(&ldsW[nrow * WP + kc]) =
            *(const half8*)((const _Float16*)Wt + nrow * 128 + kc);
    }
    __syncthreads();
    int rwb = blockIdx.x * 128 + wid * 32;
    int m = lane & 15;
    int quad = lane >> 4;
    floatx4 acc[2][CT];
#pragma unroll
    for (int t = 0; t < 2; t++)
#pragma unroll
        for (int c = 0; c < CT; c++) acc[t][c] = (floatx4){0.f, 0.f, 0.f, 0.f};

#pragma unroll
    for (int kq = 0; kq < 4; kq++) {
        int k0 = kq * 32 + quad * 8;
        half8 afr[2];
#pragma unroll
        for (int t = 0; t < 2; t++) {
            int r = rwb + t * 16 + m;
            r = r < n ? r : n - 1;  // clamp (results unused for OOB rows)
            const AT* ap = A + (size_t)r * 128 + k0;
            if constexpr (sizeof(AT) == 2) {
                afr[t] = *(const half8*)ap;
            } else {
                float4 f0 = *(const float4*)ap;
                float4 f1 = *(const float4*)(ap + 4);
                half8 h;
                h[0] = (_Float16)f0.x; h[1] = (_Float16)f0.y;
                h[2] = (_Float16)f0.z; h[3] = (_Float16)f0.w;
                h[4] = (_Float16)f1.x; h[5] = (_Float16)f1.y;
                h[6] = (_Float16)f1.z; h[7] = (_Float16)f1.w;
                afr[t] = h;
            }
        }
#pragma unroll
        for (int c = 0; c < CT; c++) {
            half8 bfr = *(const half8*)(&ldsW[(c * 16 + m) * WP + k0]);
#pragma unroll
            for (int t = 0; t < 2; t++)
                acc[t][c] =
                    __builtin_amdgcn_mfma_f32_16x16x32_f16(afr[t], bfr, acc[t][c], 0, 0, 0);
        }
    }
#pragma unroll
    for (int t = 0; t < 2; t++) {
#pragma unroll
        for (int reg = 0; reg < 4; reg++) {
            int r = rwb + t * 16 + quad * 4 + reg;
            if (r < n) {
                float dv = dinv[r];
#pragma unroll
                for (int c = 0; c < CT; c++)
                    C[(size_t)r * DOUT + c * 16 + m] = __float2half(acc[t][c][reg] * dv);
            }
        }
    }
}

// ---------------- gather-aggregate: out[d] = dinv[d] * sum xw[src] + bias ----------
template <int D, bool RELU, typename OT>
__global__ __launch_bounds__(256) void aggregate_k(const __half* __restrict__ xw,
                                                   const int* __restrict__ ptr,
                                                   const int* __restrict__ meta,
                                                   const float* __restrict__ bias,
                                                   const float* __restrict__ dinv,
                                                   OT* __restrict__ out, int n) {
    constexpr int GS = D / 8;    // lanes per row (16 or 8)
    constexpr int EPW = 64 / GS; // edges per wave-load (4 or 8)
    __shared__ int smeta[4][64];
    int lane = threadIdx.x & 63;
    int wid = threadIdx.x >> 6;
    int node = blockIdx.x * 4 + wid;
    if (node >= n) return;
    int e0 = ptr[node], e1 = ptr[node + 1];
    float dv = dinv[node];
    int sub = lane / GS;   // edge sub-slot
    int cg = lane % GS;    // column group: cols [cg*8, cg*8+8)
    const _Float16* xp = (const _Float16*)xw + cg * 8;
    float acc[8];
#pragma unroll
    for (int i = 0; i < 8; i++) acc[i] = 0.f;

    for (int base = e0; base < e1; base += 64) {
        int cnt = min(e1 - base, 64);
        if (lane < cnt) smeta[wid][lane] = meta[base + lane];
        for (int j = 0; j < cnt; j += EPW) {
            int e = j + sub;
            bool valid = e < cnt;
            int s = smeta[wid][valid ? e : 0];
            half8 v = *(const half8*)(xp + (size_t)s * D);
            float msk = valid ? 1.f : 0.f;
#pragma unroll
            for (int i = 0; i < 8; i++) acc[i] = fmaf(msk, (float)v[i], acc[i]);
        }
    }
#pragma unroll
    for (int off = GS; off < 64; off <<= 1) {
#pragma unroll
        for (int i = 0; i < 8; i++) acc[i] += __shfl_xor(acc[i], off, 64);
    }
    if (lane < GS) {
        float4 bb0 = *(const float4*)(bias + cg * 8);
        float4 bb1 = *(const float4*)(bias + cg * 8 + 4);
        float r[8];
        r[0] = acc[0] * dv + bb0.x; r[1] = acc[1] * dv + bb0.y;
        r[2] = acc[2] * dv + bb0.z; r[3] = acc[3] * dv + bb0.w;
        r[4] = acc[4] * dv + bb1.x; r[5] = acc[5] * dv + bb1.y;
        r[6] = acc[6] * dv + bb1.z; r[7] = acc[7] * dv + bb1.w;
        if (RELU) {
#pragma unroll
            for (int i = 0; i < 8; i++) r[i] = fmaxf(r[i], 0.f);
        }
        if constexpr (sizeof(OT) == 2) {
            half8 h;
#pragma unroll
            for (int i = 0; i < 8; i++) h[i] = (_Float16)r[i];
            *(half8*)((_Float16*)out + (size_t)node * D + cg * 8) = h;
        } else {
            float* op = (float*)out + (size_t)node * D + cg * 8;
            *(float4*)op = make_float4(r[0], r[1], r[2], r[3]);
            *(float4*)(op + 4) = make_float4(r[4], r[5], r[6], r[7]);
        }
    }
}

extern "C" void kernel_launch(void* const* d_in, const int* in_sizes, int n_in,
                              void* d_out, int out_size, void* d_ws, size_t ws_size,
                              hipStream_t stream) {
    const float* x = (const float*)d_in[0];
    const int* ei = (const int*)d_in[1];
    const float* W1 = (const float*)d_in[2];
    const float* b1 = (const float*)d_in[3];
    const float* W2 = (const float*)d_in[4];
    const float* b2 = (const float*)d_in[5];
    const float* W3 = (const float*)d_in[6];
    const float* b3 = (const float*)d_in[7];
    float* out = (float*)d_out;
    int N = in_sizes[0] / 128;
    int E = in_sizes[1] / 2;
    const int* row = ei;
    const int* col = ei + E;
    int T = E + N;

    char* w = (char*)d_ws;
    size_t off = 0;
    auto alloc = [&](size_t bytes) -> void* {
        void* p = w + off;
        off = (off + bytes + 511) & ~(size_t)511;
        return p;
    };
    __half* bufH = (__half*)alloc((size_t)N * 128 * 2);   // xw (dinv-scaled, fp16)
    __half* bufA = (__half*)alloc((size_t)N * 128 * 2);   // hidden h (fp16 GEMM input)
    __half* Wt1 = (__half*)alloc(16384 * 2);
    __half* Wt2 = (__half*)alloc(16384 * 2);
    __half* Wt3 = (__half*)alloc(8192 * 2);
    int* deg = (int*)alloc((size_t)N * 4);
    float* dinv = (float*)alloc((size_t)N * 4);
    int* cptr = (int*)alloc((size_t)(N + 1) * 4);
    int* meta = (int*)alloc((size_t)T * 4);
    int* bsum = (int*)alloc(4096);
    int* ovfcnt = (int*)alloc(64);
    unsigned long long* ovf = (unsigned long long*)alloc((size_t)OVFCAP * 8);
    int NB = (E + TILE - 1) / TILE;              // 782 for E=1.6M (<= MAXNB)
    int* cnts = (int*)alloc((size_t)NCH * NB * 4);
    int chunk = (N + NCH - 1) / NCH;             // 782 for N=100K (<= MAXCH)

    // staging aliases bufH+bufA (38.4MB <= 51.2MB): dead before gemm1 (stream order)
    int* stg_d = (int*)bufH;
    int* stg_s = stg_d + (size_t)NCH * NB * CSLOT;

    int nb = (N + 1023) / 1024;
    wconv_k<<<161, 256, 0, stream>>>(W1, W2, W3, Wt1, Wt2, Wt3, ovfcnt);
    part_k<<<NB, 256, 0, stream>>>(row, col, E, chunk, NB, stg_d, stg_s, cnts, ovf, ovfcnt);
    degcnt_k<<<NCH, 256, 0, stream>>>(stg_d, cnts, NB, N, chunk, ovf, ovfcnt, deg, dinv);
    scan_p1<<<nb, 256, 0, stream>>>(deg, N, bsum);
    scan_p2<<<1, 256, 0, stream>>>(bsum, nb);
    scan_p3<<<nb, 256, 0, stream>>>(deg, N, bsum, cptr);
    fill3_k<<<NCH, 256, 0, stream>>>(stg_d, stg_s, cnts, NB, cptr, N, chunk, ovf, ovfcnt, meta);

    int gb = (N + 127) / 128;
    int ab = (N + 3) / 4;
    gemm_mfma<float, 128><<<gb, 256, 0, stream>>>(x, Wt1, dinv, bufH, N);
    aggregate_k<128, true, __half><<<ab, 256, 0, stream>>>(bufH, cptr, meta, b1, dinv, bufA, N);
    gemm_mfma<__half, 128><<<gb, 256, 0, stream>>>(bufA, Wt2, dinv, bufH, N);
    aggregate_k<128, true, __half><<<ab, 256, 0, stream>>>(bufH, cptr, meta, b2, dinv, bufA, N);
    gemm_mfma<__half, 64><<<gb, 256, 0, stream>>>(bufA, Wt3, dinv, bufH, N);
    aggregate_k<64, false, float><<<ab, 256, 0, stream>>>(bufH, cptr, meta, b3, dinv, out, N);
}

// Round 5
// 395.581 us; speedup vs baseline: 1.2405x; 1.0290x over previous
//
#include <hip/hip_runtime.h>
#include <hip/hip_fp16.h>

typedef _Float16 half8 __attribute__((ext_vector_type(8)));
typedef float floatx4 __attribute__((ext_vector_type(4)));

#define NCH 128      // dst chunks (one fill/degcnt block per chunk)
#define TILE 2048    // edges per part_k block
#define CSLOT 48     // slots per (chunk,block) cell: mean 16, +8 sigma
#define MAXNB 1024   // max part_k blocks supported (E <= 2M)
#define MAXCH 1024   // max nodes per chunk supported (N <= 128K)
#define OVFCAP 65536 // overflow spill capacity (pairs)

// ---------------- weight convert + transpose: Wt[n][k] = (half)W[k][n] ----------
// (also zeroes the overflow counter: idx 40960)
__global__ __launch_bounds__(256) void wconv_k(const float* __restrict__ W1,
                                               const float* __restrict__ W2,
                                               const float* __restrict__ W3,
                                               __half* __restrict__ Wt1,
                                               __half* __restrict__ Wt2,
                                               __half* __restrict__ Wt3,
                                               int* __restrict__ ovfcnt) {
    int idx = blockIdx.x * 256 + threadIdx.x;
    if (idx < 16384) {
        int k = idx >> 7, nn = idx & 127;
        Wt1[nn * 128 + k] = __float2half(W1[idx]);
    } else if (idx < 32768) {
        int j = idx - 16384;
        int k = j >> 7, nn = j & 127;
        Wt2[nn * 128 + k] = __float2half(W2[j]);
    } else if (idx < 40960) {
        int j = idx - 32768;
        int k = j >> 6, nn = j & 63;
        Wt3[nn * 128 + k] = __float2half(W3[j]);
    } else if (idx == 40960) {
        *ovfcnt = 0;
    }
}

// ---------------- pass 1: deterministic-cell partition (NO global atomics) -------
__global__ __launch_bounds__(256) void part_k(const int* __restrict__ row,
                                              const int* __restrict__ col, int E,
                                              int chunk, int NB,
                                              int* __restrict__ stg_d,
                                              int* __restrict__ stg_s,
                                              int* __restrict__ cnts,
                                              unsigned long long* __restrict__ ovf,
                                              int* __restrict__ ovfcnt) {
    __shared__ int bd[NCH][CSLOT];
    __shared__ int bs[NCH][CSLOT];
    __shared__ int lcnt[NCH];
    __shared__ int lpref[NCH + 1];
    int tid = threadIdx.x;
    int b = blockIdx.x;
    for (int i = tid; i < NCH; i += 256) lcnt[i] = 0;
    __syncthreads();

    int i0 = b * TILE + tid * 8;
    int sv[8], dv[8];
    int nv = 0;
    if (i0 + 7 < E && (E & 3) == 0) {  // col = ei+E stays 16B-aligned iff E%4==0
        int4 r0 = *(const int4*)(row + i0);
        int4 r1 = *(const int4*)(row + i0 + 4);
        int4 c0 = *(const int4*)(col + i0);
        int4 c1 = *(const int4*)(col + i0 + 4);
        sv[0] = r0.x; sv[1] = r0.y; sv[2] = r0.z; sv[3] = r0.w;
        sv[4] = r1.x; sv[5] = r1.y; sv[6] = r1.z; sv[7] = r1.w;
        dv[0] = c0.x; dv[1] = c0.y; dv[2] = c0.z; dv[3] = c0.w;
        dv[4] = c1.x; dv[5] = c1.y; dv[6] = c1.z; dv[7] = c1.w;
        nv = 8;
    } else {
#pragma unroll
        for (int j = 0; j < 8; j++) {
            if (i0 + j < E) { sv[nv] = row[i0 + j]; dv[nv] = col[i0 + j]; nv++; }
        }
    }
#pragma unroll 8
    for (int j = 0; j < nv; j++) {
        int d = dv[j], s = sv[j];
        int c = d / chunk;  // exact integer binning (must match fill/degcnt ranges)
        int r = atomicAdd(&lcnt[c], 1);
        if (r < CSLOT) {
            bd[c][r] = d;
            bs[c][r] = s;
        } else {  // ~1e-17/cell; correctness guard
            int o = atomicAdd(ovfcnt, 1);
            if (o < OVFCAP)
                ovf[o] = ((unsigned long long)(unsigned)d << 32) | (unsigned)s;
        }
    }
    __syncthreads();
    if (tid == 0) {
        int a = 0;
#pragma unroll
        for (int c = 0; c < NCH; c++) {
            lpref[c] = a;
            a += min(lcnt[c], CSLOT);
        }
        lpref[NCH] = a;
    }
    __syncthreads();
    for (int c = tid; c < NCH; c += 256) cnts[(size_t)c * NB + b] = min(lcnt[c], CSLOT);
    int total = lpref[NCH];
    for (int f = tid; f < total; f += 256) {
        int lo = 0, hi = NCH;  // binary search: largest c with lpref[c] <= f
        while (hi - lo > 1) {
            int mid = (lo + hi) >> 1;
            if (lpref[mid] <= f) lo = mid; else hi = mid;
        }
        int slot = f - lpref[lo];
        size_t cell = ((size_t)lo * NB + b) * CSLOT;
        stg_d[cell + slot] = bd[lo][slot];
        stg_s[cell + slot] = bs[lo][slot];
    }
}

// ---------------- pass 2a: per-chunk degree histogram (LDS only) -----------------
__global__ __launch_bounds__(256) void degcnt_k(const int* __restrict__ stg_d,
                                                const int* __restrict__ cnts, int NB,
                                                int N, int chunk,
                                                const unsigned long long* __restrict__ ovf,
                                                const int* __restrict__ ovfcnt,
                                                int* __restrict__ deg,
                                                float* __restrict__ dinv) {
    __shared__ int hist[MAXCH];
    __shared__ int lc[MAXNB];
    int c = blockIdx.x, tid = threadIdx.x;
    int dlo = c * chunk;
    int dhi = min(N, dlo + chunk);
    int csz = dhi - dlo;
    if (csz <= 0) return;
    for (int i = tid; i < csz; i += 256) hist[i] = 1;  // self-loop
    for (int i = tid; i < NB; i += 256) lc[i] = cnts[(size_t)c * NB + i];
    __syncthreads();
    for (int b0 = tid >> 4; b0 < NB; b0 += 16) {
        int cnt = lc[b0];
        size_t base = ((size_t)c * NB + b0) * CSLOT;
        for (int slot = tid & 15; slot < cnt; slot += 16) {
            int d = stg_d[base + slot];
            atomicAdd(&hist[d - dlo], 1);
        }
    }
    __syncthreads();
    int oc = min(*ovfcnt, OVFCAP);
    for (int i = tid; i < oc; i += 256) {
        int d = (int)(ovf[i] >> 32);
        if (d >= dlo && d < dhi) atomicAdd(&hist[d - dlo], 1);
    }
    __syncthreads();
    for (int i = tid; i < csz; i += 256) {
        int dg = hist[i];
        deg[dlo + i] = dg;
        dinv[dlo + i] = rsqrtf((float)dg);
    }
}

// ---------------- 3-phase exclusive scan of deg -> col_ptr ----------------
__global__ __launch_bounds__(256) void scan_p1(const int* __restrict__ deg, int n,
                                               int* __restrict__ bsum) {
    __shared__ int lds[256];
    int t = threadIdx.x;
    int base = blockIdx.x * 1024 + t * 4;
    int s = 0;
#pragma unroll
    for (int i = 0; i < 4; i++) {
        int idx = base + i;
        if (idx < n) s += deg[idx];
    }
    lds[t] = s;
    __syncthreads();
    for (int o = 128; o > 0; o >>= 1) {
        if (t < o) lds[t] += lds[t + o];
        __syncthreads();
    }
    if (t == 0) bsum[blockIdx.x] = lds[0];
}

__global__ __launch_bounds__(256) void scan_p2(int* __restrict__ bsum, int nb) {
    __shared__ int lds[256];
    int t = threadIdx.x;
    int v = (t < nb) ? bsum[t] : 0;
    lds[t] = v;
    __syncthreads();
    for (int o = 1; o < 256; o <<= 1) {
        int tmp = 0;
        if (t >= o) tmp = lds[t - o];
        __syncthreads();
        lds[t] += tmp;
        __syncthreads();
    }
    if (t < nb) bsum[t] = lds[t] - v;  // exclusive
}

__global__ __launch_bounds__(256) void scan_p3(const int* __restrict__ deg, int n,
                                               const int* __restrict__ bsum,
                                               int* __restrict__ cptr) {
    __shared__ int lds[256];
    int t = threadIdx.x;
    int base = blockIdx.x * 1024 + t * 4;
    int v[4];
    int s = 0;
#pragma unroll
    for (int i = 0; i < 4; i++) {
        int idx = base + i;
        v[i] = (idx < n) ? deg[idx] : 0;
        s += v[i];
    }
    lds[t] = s;
    __syncthreads();
    for (int o = 1; o < 256; o <<= 1) {
        int tmp = 0;
        if (t >= o) tmp = lds[t - o];
        __syncthreads();
        lds[t] += tmp;
        __syncthreads();
    }
    int off = bsum[blockIdx.x] + (lds[t] - s);
#pragma unroll
    for (int i = 0; i < 4; i++) {
        int idx = base + i;
        if (idx < n) {
            cptr[idx] = off;
            off += v[i];
            if (idx == n - 1) cptr[n] = off;
        }
    }
}

// ---------------- pass 2b: per-chunk scatter with LDS cursors (NO global atomics)
__global__ __launch_bounds__(256) void fill3_k(const int* __restrict__ stg_d,
                                               const int* __restrict__ stg_s,
                                               const int* __restrict__ cnts, int NB,
                                               const int* __restrict__ cptr,
                                               int N, int chunk,
                                               const unsigned long long* __restrict__ ovf,
                                               const int* __restrict__ ovfcnt,
                                               int* __restrict__ meta) {
    __shared__ int cur[MAXCH];
    __shared__ int lc[MAXNB];
    int c = blockIdx.x, tid = threadIdx.x;
    int dlo = c * chunk;
    int dhi = min(N, dlo + chunk);
    int csz = dhi - dlo;
    if (csz <= 0) return;
    for (int i = tid; i < csz; i += 256) cur[i] = cptr[dlo + i];
    for (int i = tid; i < NB; i += 256) lc[i] = cnts[(size_t)c * NB + i];
    __syncthreads();
    for (int b0 = tid >> 4; b0 < NB; b0 += 16) {
        int cnt = lc[b0];
        size_t base = ((size_t)c * NB + b0) * CSLOT;
        for (int slot = tid & 15; slot < cnt; slot += 16) {
            int d = stg_d[base + slot];
            int s = stg_s[base + slot];
            int p = atomicAdd(&cur[d - dlo], 1);
            meta[p] = s;
        }
    }
    // self-loops
    for (int i = tid; i < csz; i += 256) {
        int p = atomicAdd(&cur[i], 1);
        meta[p] = dlo + i;
    }
    // overflow spills (normally zero)
    int oc = min(*ovfcnt, OVFCAP);
    for (int i = tid; i < oc; i += 256) {
        unsigned long long v = ovf[i];
        int d = (int)(v >> 32);
        if (d >= dlo && d < dhi) {
            int p = atomicAdd(&cur[d - dlo], 1);
            meta[p] = (int)(v & 0xffffffffull);
        }
    }
}

// ---------------- f16 MFMA GEMM: C[n][DOUT] = (half)(dinv[r] * A[n][128] @ W) ------
template <typename AT, int DOUT>
__global__ __launch_bounds__(256) void gemm_mfma(const AT* __restrict__ A,
                                                 const __half* __restrict__ Wt,
                                                 const float* __restrict__ dinv,
                                                 __half* __restrict__ C, int n) {
    constexpr int CT = DOUT / 16;  // col tiles: 8 or 4
    constexpr int WP = 136;        // padded LDS stride (halves)
    __shared__ _Float16 ldsW[DOUT * WP];
    int tid = threadIdx.x;
    int lane = tid & 63;
    int wid = tid >> 6;
    for (int i = tid; i < DOUT * 16; i += 256) {
        int nrow = i >> 4;
        int kc = (i & 15) * 8;
        *(half8*)(&ldsW[nrow * WP + kc]) =
            *(const half8*)((const _Float16*)Wt + nrow * 128 + kc);
    }
    __syncthreads();
    int rwb = blockIdx.x * 128 + wid * 32;
    int m = lane & 15;
    int quad = lane >> 4;
    floatx4 acc[2][CT];
#pragma unroll
    for (int t = 0; t < 2; t++)
#pragma unroll
        for (int c = 0; c < CT; c++) acc[t][c] = (floatx4){0.f, 0.f, 0.f, 0.f};

#pragma unroll
    for (int kq = 0; kq < 4; kq++) {
        int k0 = kq * 32 + quad * 8;
        half8 afr[2];
#pragma unroll
        for (int t = 0; t < 2; t++) {
            int r = rwb + t * 16 + m;
            r = r < n ? r : n - 1;  // clamp (results unused for OOB rows)
            const AT* ap = A + (size_t)r * 128 + k0;
            if constexpr (sizeof(AT) == 2) {
                afr[t] = *(const half8*)ap;
            } else {
                float4 f0 = *(const float4*)ap;
                float4 f1 = *(const float4*)(ap + 4);
                half8 h;
                h[0] = (_Float16)f0.x; h[1] = (_Float16)f0.y;
                h[2] = (_Float16)f0.z; h[3] = (_Float16)f0.w;
                h[4] = (_Float16)f1.x; h[5] = (_Float16)f1.y;
                h[6] = (_Float16)f1.z; h[7] = (_Float16)f1.w;
                afr[t] = h;
            }
        }
#pragma unroll
        for (int c = 0; c < CT; c++) {
            half8 bfr = *(const half8*)(&ldsW[(c * 16 + m) * WP + k0]);
#pragma unroll
            for (int t = 0; t < 2; t++)
                acc[t][c] =
                    __builtin_amdgcn_mfma_f32_16x16x32_f16(afr[t], bfr, acc[t][c], 0, 0, 0);
        }
    }
#pragma unroll
    for (int t = 0; t < 2; t++) {
#pragma unroll
        for (int reg = 0; reg < 4; reg++) {
            int r = rwb + t * 16 + quad * 4 + reg;
            if (r < n) {
                float dv = dinv[r];
#pragma unroll
                for (int c = 0; c < CT; c++)
                    C[(size_t)r * DOUT + c * 16 + m] = __float2half(acc[t][c][reg] * dv);
            }
        }
    }
}

// ---------------- gather-aggregate: out[d] = dinv[d] * sum xw[src] + bias ----------
// R4 counters (HBM 43%, VALU 45%, occ 74%) = latency-bound gather: one dependent
// 16B load in flight per lane. Fix: issue UNROLL independent edge-groups of
// gathers back-to-back (all LDS index reads -> all global loads -> all FMAs) for
// 4x memory-level parallelism. Invalid slots re-gather the slot-0 row (L1-hot).
template <int D, bool RELU, typename OT>
__global__ __launch_bounds__(256) void aggregate_k(const __half* __restrict__ xw,
                                                   const int* __restrict__ ptr,
                                                   const int* __restrict__ meta,
                                                   const float* __restrict__ bias,
                                                   const float* __restrict__ dinv,
                                                   OT* __restrict__ out, int n) {
    constexpr int GS = D / 8;    // lanes per row (16 or 8)
    constexpr int EPW = 64 / GS; // edges per wave-load (4 or 8)
    constexpr int UNR = (EPW == 4) ? 4 : 2;  // groups in flight (step = 16 edges)
    __shared__ int smeta[4][64];
    int lane = threadIdx.x & 63;
    int wid = threadIdx.x >> 6;
    int node = blockIdx.x * 4 + wid;
    if (node >= n) return;
    int e0 = ptr[node], e1 = ptr[node + 1];
    float dv = dinv[node];
    int sub = lane / GS;   // edge sub-slot
    int cg = lane % GS;    // column group: cols [cg*8, cg*8+8)
    const _Float16* xp = (const _Float16*)xw + cg * 8;
    float acc[8];
#pragma unroll
    for (int i = 0; i < 8; i++) acc[i] = 0.f;

    for (int base = e0; base < e1; base += 64) {
        int cnt = min(e1 - base, 64);
        if (lane < cnt) smeta[wid][lane] = meta[base + lane];
        for (int j = 0; j < cnt; j += UNR * EPW) {
            int sreg[UNR];
            float mk[UNR];
#pragma unroll
            for (int u = 0; u < UNR; u++) {
                int e = j + u * EPW + sub;
                bool val = e < cnt;
                sreg[u] = smeta[wid][val ? e : 0];
                mk[u] = val ? 1.f : 0.f;
            }
            half8 vreg[UNR];
#pragma unroll
            for (int u = 0; u < UNR; u++)
                vreg[u] = *(const half8*)(xp + (size_t)sreg[u] * D);
#pragma unroll
            for (int u = 0; u < UNR; u++)
#pragma unroll
                for (int i = 0; i < 8; i++)
                    acc[i] = fmaf(mk[u], (float)vreg[u][i], acc[i]);
        }
    }
#pragma unroll
    for (int off = GS; off < 64; off <<= 1) {
#pragma unroll
        for (int i = 0; i < 8; i++) acc[i] += __shfl_xor(acc[i], off, 64);
    }
    if (lane < GS) {
        float4 bb0 = *(const float4*)(bias + cg * 8);
        float4 bb1 = *(const float4*)(bias + cg * 8 + 4);
        float r[8];
        r[0] = acc[0] * dv + bb0.x; r[1] = acc[1] * dv + bb0.y;
        r[2] = acc[2] * dv + bb0.z; r[3] = acc[3] * dv + bb0.w;
        r[4] = acc[4] * dv + bb1.x; r[5] = acc[5] * dv + bb1.y;
        r[6] = acc[6] * dv + bb1.z; r[7] = acc[7] * dv + bb1.w;
        if (RELU) {
#pragma unroll
            for (int i = 0; i < 8; i++) r[i] = fmaxf(r[i], 0.f);
        }
        if constexpr (sizeof(OT) == 2) {
            half8 h;
#pragma unroll
            for (int i = 0; i < 8; i++) h[i] = (_Float16)r[i];
            *(half8*)((_Float16*)out + (size_t)node * D + cg * 8) = h;
        } else {
            float* op = (float*)out + (size_t)node * D + cg * 8;
            *(float4*)op = make_float4(r[0], r[1], r[2], r[3]);
            *(float4*)(op + 4) = make_float4(r[4], r[5], r[6], r[7]);
        }
    }
}

extern "C" void kernel_launch(void* const* d_in, const int* in_sizes, int n_in,
                              void* d_out, int out_size, void* d_ws, size_t ws_size,
                              hipStream_t stream) {
    const float* x = (const float*)d_in[0];
    const int* ei = (const int*)d_in[1];
    const float* W1 = (const float*)d_in[2];
    const float* b1 = (const float*)d_in[3];
    const float* W2 = (const float*)d_in[4];
    const float* b2 = (const float*)d_in[5];
    const float* W3 = (const float*)d_in[6];
    const float* b3 = (const float*)d_in[7];
    float* out = (float*)d_out;
    int N = in_sizes[0] / 128;
    int E = in_sizes[1] / 2;
    const int* row = ei;
    const int* col = ei + E;
    int T = E + N;

    char* w = (char*)d_ws;
    size_t off = 0;
    auto alloc = [&](size_t bytes) -> void* {
        void* p = w + off;
        off = (off + bytes + 511) & ~(size_t)511;
        return p;
    };
    __half* bufH = (__half*)alloc((size_t)N * 128 * 2);   // xw (dinv-scaled, fp16)
    __half* bufA = (__half*)alloc((size_t)N * 128 * 2);   // hidden h (fp16 GEMM input)
    __half* Wt1 = (__half*)alloc(16384 * 2);
    __half* Wt2 = (__half*)alloc(16384 * 2);
    __half* Wt3 = (__half*)alloc(8192 * 2);
    int* deg = (int*)alloc((size_t)N * 4);
    float* dinv = (float*)alloc((size_t)N * 4);
    int* cptr = (int*)alloc((size_t)(N + 1) * 4);
    int* meta = (int*)alloc((size_t)T * 4);
    int* bsum = (int*)alloc(4096);
    int* ovfcnt = (int*)alloc(64);
    unsigned long long* ovf = (unsigned long long*)alloc((size_t)OVFCAP * 8);
    int NB = (E + TILE - 1) / TILE;              // 782 for E=1.6M (<= MAXNB)
    int* cnts = (int*)alloc((size_t)NCH * NB * 4);
    int chunk = (N + NCH - 1) / NCH;             // 782 for N=100K (<= MAXCH)

    // staging aliases bufH+bufA (38.4MB <= 51.2MB): dead before gemm1 (stream order)
    int* stg_d = (int*)bufH;
    int* stg_s = stg_d + (size_t)NCH * NB * CSLOT;

    int nb = (N + 1023) / 1024;
    wconv_k<<<161, 256, 0, stream>>>(W1, W2, W3, Wt1, Wt2, Wt3, ovfcnt);
    part_k<<<NB, 256, 0, stream>>>(row, col, E, chunk, NB, stg_d, stg_s, cnts, ovf, ovfcnt);
    degcnt_k<<<NCH, 256, 0, stream>>>(stg_d, cnts, NB, N, chunk, ovf, ovfcnt, deg, dinv);
    scan_p1<<<nb, 256, 0, stream>>>(deg, N, bsum);
    scan_p2<<<1, 256, 0, stream>>>(bsum, nb);
    scan_p3<<<nb, 256, 0, stream>>>(deg, N, bsum, cptr);
    fill3_k<<<NCH, 256, 0, stream>>>(stg_d, stg_s, cnts, NB, cptr, N, chunk, ovf, ovfcnt, meta);

    int gb = (N + 127) / 128;
    int ab = (N + 3) / 4;
    gemm_mfma<float, 128><<<gb, 256, 0, stream>>>(x, Wt1, dinv, bufH, N);
    aggregate_k<128, true, __half><<<ab, 256, 0, stream>>>(bufH, cptr, meta, b1, dinv, bufA, N);
    gemm_mfma<__half, 128><<<gb, 256, 0, stream>>>(bufA, Wt2, dinv, bufH, N);
    aggregate_k<128, true, __half><<<ab, 256, 0, stream>>>(bufH, cptr, meta, b2, dinv, bufA, N);
    gemm_mfma<__half, 64><<<gb, 256, 0, stream>>>(bufA, Wt3, dinv, bufH, N);
    aggregate_k<64, false, float><<<ab, 256, 0, stream>>>(bufH, cptr, meta, b3, dinv, out, N);
}

// Round 6
// 376.145 us; speedup vs baseline: 1.3046x; 1.0517x over previous
//
#include <hip/hip_runtime.h>
#include <hip/hip_fp16.h>

typedef _Float16 half8 __attribute__((ext_vector_type(8)));
typedef float floatx4 __attribute__((ext_vector_type(4)));

#define NCH 128      // dst chunks (one csr block per chunk)
#define TILE 2048    // edges per part_k block
#define CSLOT 48     // slots per (chunk,block) cell: mean 16, +8 sigma
#define MAXNB 1024   // max part_k blocks supported (E <= 2M)
#define MAXCH 1024   // max nodes per chunk supported (N <= 128K)
#define OVFCAP 65536 // overflow spill capacity (pairs)

// ---------------- weight convert + transpose: Wt[n][k] = (half)W[k][n] ----------
// (also zeroes the overflow counter: idx 40960)
__global__ __launch_bounds__(256) void wconv_k(const float* __restrict__ W1,
                                               const float* __restrict__ W2,
                                               const float* __restrict__ W3,
                                               __half* __restrict__ Wt1,
                                               __half* __restrict__ Wt2,
                                               __half* __restrict__ Wt3,
                                               int* __restrict__ ovfcnt) {
    int idx = blockIdx.x * 256 + threadIdx.x;
    if (idx < 16384) {
        int k = idx >> 7, nn = idx & 127;
        Wt1[nn * 128 + k] = __float2half(W1[idx]);
    } else if (idx < 32768) {
        int j = idx - 16384;
        int k = j >> 7, nn = j & 127;
        Wt2[nn * 128 + k] = __float2half(W2[j]);
    } else if (idx < 40960) {
        int j = idx - 32768;
        int k = j >> 6, nn = j & 63;
        Wt3[nn * 128 + k] = __float2half(W3[j]);
    } else if (idx == 40960) {
        *ovfcnt = 0;
    }
}

// ---------------- pass 1: deterministic-cell partition (NO global atomics) -------
__global__ __launch_bounds__(256) void part_k(const int* __restrict__ row,
                                              const int* __restrict__ col, int E,
                                              int chunk, int NB,
                                              int* __restrict__ stg_d,
                                              int* __restrict__ stg_s,
                                              int* __restrict__ cnts,
                                              unsigned long long* __restrict__ ovf,
                                              int* __restrict__ ovfcnt) {
    __shared__ int bd[NCH][CSLOT];
    __shared__ int bs[NCH][CSLOT];
    __shared__ int lcnt[NCH];
    __shared__ int lpref[NCH + 1];
    int tid = threadIdx.x;
    int b = blockIdx.x;
    for (int i = tid; i < NCH; i += 256) lcnt[i] = 0;
    __syncthreads();

    int i0 = b * TILE + tid * 8;
    int sv[8], dv[8];
    int nv = 0;
    if (i0 + 7 < E && (E & 3) == 0) {  // col = ei+E stays 16B-aligned iff E%4==0
        int4 r0 = *(const int4*)(row + i0);
        int4 r1 = *(const int4*)(row + i0 + 4);
        int4 c0 = *(const int4*)(col + i0);
        int4 c1 = *(const int4*)(col + i0 + 4);
        sv[0] = r0.x; sv[1] = r0.y; sv[2] = r0.z; sv[3] = r0.w;
        sv[4] = r1.x; sv[5] = r1.y; sv[6] = r1.z; sv[7] = r1.w;
        dv[0] = c0.x; dv[1] = c0.y; dv[2] = c0.z; dv[3] = c0.w;
        dv[4] = c1.x; dv[5] = c1.y; dv[6] = c1.z; dv[7] = c1.w;
        nv = 8;
    } else {
#pragma unroll
        for (int j = 0; j < 8; j++) {
            if (i0 + j < E) { sv[nv] = row[i0 + j]; dv[nv] = col[i0 + j]; nv++; }
        }
    }
#pragma unroll 8
    for (int j = 0; j < nv; j++) {
        int d = dv[j], s = sv[j];
        int c = d / chunk;  // exact integer binning (must match csr chunk ranges)
        int r = atomicAdd(&lcnt[c], 1);
        if (r < CSLOT) {
            bd[c][r] = d;
            bs[c][r] = s;
        } else {  // ~1e-17/cell; correctness guard
            int o = atomicAdd(ovfcnt, 1);
            if (o < OVFCAP)
                ovf[o] = ((unsigned long long)(unsigned)d << 32) | (unsigned)s;
        }
    }
    __syncthreads();
    if (tid == 0) {
        int a = 0;
#pragma unroll
        for (int c = 0; c < NCH; c++) {
            lpref[c] = a;
            a += min(lcnt[c], CSLOT);
        }
        lpref[NCH] = a;
    }
    __syncthreads();
    for (int c = tid; c < NCH; c += 256) cnts[(size_t)c * NB + b] = min(lcnt[c], CSLOT);
    int total = lpref[NCH];
    for (int f = tid; f < total; f += 256) {
        int lo = 0, hi = NCH;  // binary search: largest c with lpref[c] <= f
        while (hi - lo > 1) {
            int mid = (lo + hi) >> 1;
            if (lpref[mid] <= f) lo = mid; else hi = mid;
        }
        int slot = f - lpref[lo];
        size_t cell = ((size_t)lo * NB + b) * CSLOT;
        stg_d[cell + slot] = bd[lo][slot];
        stg_s[cell + slot] = bs[lo][slot];
    }
}

// ---------------- pass 2a: per-chunk degree histogram + deg/dinv + chunk sums ----
// One block per chunk, LDS atomics only. Replaces degcnt + deg_init + dinv.
__global__ __launch_bounds__(512) void csr_hist_k(const int* __restrict__ stg_d,
                                                  const int* __restrict__ cnts, int NB,
                                                  int N, int chunk,
                                                  const unsigned long long* __restrict__ ovf,
                                                  const int* __restrict__ ovfcnt,
                                                  int* __restrict__ deg,
                                                  float* __restrict__ dinv,
                                                  int* __restrict__ csum) {
    __shared__ int hist[MAXCH];
    __shared__ int red[512];
    int c = blockIdx.x, tid = threadIdx.x;
    int dlo = c * chunk;
    int dhi = min(N, dlo + chunk);
    int csz = dhi - dlo;
    if (csz <= 0) {
        if (tid == 0) csum[c] = 0;
        return;
    }
    for (int i = tid; i < csz; i += 512) hist[i] = 1;  // self-loop
    __syncthreads();
    for (int b0 = tid >> 4; b0 < NB; b0 += 32) {
        int cnt = cnts[(size_t)c * NB + b0];
        size_t base = ((size_t)c * NB + b0) * CSLOT;
        for (int slot = tid & 15; slot < cnt; slot += 16)
            atomicAdd(&hist[stg_d[base + slot] - dlo], 1);
    }
    int oc = min(*ovfcnt, OVFCAP);
    for (int i = tid; i < oc; i += 512) {
        int d = (int)(ovf[i] >> 32);
        if (d >= dlo && d < dhi) atomicAdd(&hist[d - dlo], 1);
    }
    __syncthreads();
    int t = 0;
    for (int i = tid; i < csz; i += 512) {
        int dg = hist[i];
        deg[dlo + i] = dg;
        dinv[dlo + i] = rsqrtf((float)dg);
        t += dg;
    }
    red[tid] = t;
    __syncthreads();
    for (int o = 256; o > 0; o >>= 1) {
        if (tid < o) red[tid] += red[tid + o];
        __syncthreads();
    }
    if (tid == 0) csum[c] = red[0];
}

// ---------------- pass 2b: per-chunk scan + scatter (replaces scan_p1/p2/p3+fill) -
// Each block redundantly reduces the 128-entry csum (512B, L2-hot) for its chunk
// base -- no cross-block sync. Then local exclusive scan of deg slice -> cptr/cur,
// then places pairs via LDS-cursor atomics. NO global atomics anywhere.
__global__ __launch_bounds__(512) void csr_fill_k(const int* __restrict__ stg_d,
                                                  const int* __restrict__ stg_s,
                                                  const int* __restrict__ cnts, int NB,
                                                  const int* __restrict__ deg,
                                                  const int* __restrict__ csum,
                                                  int N, int chunk,
                                                  const unsigned long long* __restrict__ ovf,
                                                  const int* __restrict__ ovfcnt,
                                                  int* __restrict__ cptr,
                                                  int* __restrict__ meta) {
    __shared__ int cur[MAXCH];
    __shared__ int sc[512];
    int c = blockIdx.x, tid = threadIdx.x;
    int dlo = c * chunk;
    int dhi = min(N, dlo + chunk);
    int csz = dhi - dlo;
    if (csz <= 0) return;

    // chunk base = sum of csum[0..c)
    sc[tid] = (tid < NCH && tid < c) ? csum[tid] : 0;
    __syncthreads();
    for (int o = 256; o > 0; o >>= 1) {
        if (tid < o) sc[tid] += sc[tid + o];
        __syncthreads();
    }
    int cbase = sc[0];
    __syncthreads();

    // local exclusive scan of deg slice (2 elems/thread, Hillis-Steele on partials)
    int i0 = tid * 2;
    int v0 = (i0 < csz) ? deg[dlo + i0] : 0;
    int v1 = (i0 + 1 < csz) ? deg[dlo + i0 + 1] : 0;
    int s = v0 + v1;
    sc[tid] = s;
    __syncthreads();
    for (int o = 1; o < 512; o <<= 1) {
        int tmp = 0;
        if (tid >= o) tmp = sc[tid - o];
        __syncthreads();
        sc[tid] += tmp;
        __syncthreads();
    }
    int off = cbase + sc[tid] - s;  // exclusive prefix
    if (i0 < csz) {
        cur[i0] = off;
        cptr[dlo + i0] = off;
        off += v0;
        if (i0 + 1 < csz) {
            cur[i0 + 1] = off;
            cptr[dlo + i0 + 1] = off;
        }
    }
    if (dhi == N && tid == 511) cptr[N] = cbase + sc[511];  // total end
    __syncthreads();

    // place staged pairs
    for (int b0 = tid >> 4; b0 < NB; b0 += 32) {
        int cnt = cnts[(size_t)c * NB + b0];
        size_t base = ((size_t)c * NB + b0) * CSLOT;
        for (int slot = tid & 15; slot < cnt; slot += 16) {
            int d = stg_d[base + slot];
            int sv = stg_s[base + slot];
            int p = atomicAdd(&cur[d - dlo], 1);
            meta[p] = sv;
        }
    }
    // self-loops
    for (int i = tid; i < csz; i += 512) {
        int p = atomicAdd(&cur[i], 1);
        meta[p] = dlo + i;
    }
    // overflow spills (normally zero)
    int oc = min(*ovfcnt, OVFCAP);
    for (int i = tid; i < oc; i += 512) {
        unsigned long long v = ovf[i];
        int d = (int)(v >> 32);
        if (d >= dlo && d < dhi) {
            int p = atomicAdd(&cur[d - dlo], 1);
            meta[p] = (int)(v & 0xffffffffull);
        }
    }
}

// ---------------- f16 MFMA GEMM: C[n][DOUT] = (half)(dinv[r] * A[n][128] @ W) ------
// Epilogue also zeroes row n of C (the aggregate's "zero row" for padded slots).
template <typename AT, int DOUT>
__global__ __launch_bounds__(256) void gemm_mfma(const AT* __restrict__ A,
                                                 const __half* __restrict__ Wt,
                                                 const float* __restrict__ dinv,
                                                 __half* __restrict__ C, int n) {
    constexpr int CT = DOUT / 16;  // col tiles: 8 or 4
    constexpr int WP = 136;        // padded LDS stride (halves)
    __shared__ _Float16 ldsW[DOUT * WP];
    int tid = threadIdx.x;
    int lane = tid & 63;
    int wid = tid >> 6;
    for (int i = tid; i < DOUT * 16; i += 256) {
        int nrow = i >> 4;
        int kc = (i & 15) * 8;
        *(half8*)(&ldsW[nrow * WP + kc]) =
            *(const half8*)((const _Float16*)Wt + nrow * 128 + kc);
    }
    __syncthreads();
    int rwb = blockIdx.x * 128 + wid * 32;
    int m = lane & 15;
    int quad = lane >> 4;
    floatx4 acc[2][CT];
#pragma unroll
    for (int t = 0; t < 2; t++)
#pragma unroll
        for (int c = 0; c < CT; c++) acc[t][c] = (floatx4){0.f, 0.f, 0.f, 0.f};

#pragma unroll
    for (int kq = 0; kq < 4; kq++) {
        int k0 = kq * 32 + quad * 8;
        half8 afr[2];
#pragma unroll
        for (int t = 0; t < 2; t++) {
            int r = rwb + t * 16 + m;
            r = r < n ? r : n - 1;  // clamp (results unused for OOB rows)
            const AT* ap = A + (size_t)r * 128 + k0;
            if constexpr (sizeof(AT) == 2) {
                afr[t] = *(const half8*)ap;
            } else {
                float4 f0 = *(const float4*)ap;
                float4 f1 = *(const float4*)(ap + 4);
                half8 h;
                h[0] = (_Float16)f0.x; h[1] = (_Float16)f0.y;
                h[2] = (_Float16)f0.z; h[3] = (_Float16)f0.w;
                h[4] = (_Float16)f1.x; h[5] = (_Float16)f1.y;
                h[6] = (_Float16)f1.z; h[7] = (_Float16)f1.w;
                afr[t] = h;
            }
        }
#pragma unroll
        for (int c = 0; c < CT; c++) {
            half8 bfr = *(const half8*)(&ldsW[(c * 16 + m) * WP + k0]);
#pragma unroll
            for (int t = 0; t < 2; t++)
                acc[t][c] =
                    __builtin_amdgcn_mfma_f32_16x16x32_f16(afr[t], bfr, acc[t][c], 0, 0, 0);
        }
    }
#pragma unroll
    for (int t = 0; t < 2; t++) {
#pragma unroll
        for (int reg = 0; reg < 4; reg++) {
            int r = rwb + t * 16 + quad * 4 + reg;
            if (r < n) {
                float dv = dinv[r];
#pragma unroll
                for (int c = 0; c < CT; c++)
                    C[(size_t)r * DOUT + c * 16 + m] = __float2half(acc[t][c][reg] * dv);
            }
        }
    }
    if (blockIdx.x == 0 && tid < DOUT / 8) {  // zero row n (aggregate pad target)
        half8 z = (half8){0, 0, 0, 0, 0, 0, 0, 0};
        *(half8*)((_Float16*)C + (size_t)n * DOUT + tid * 8) = z;
    }
}

// ---------------- gather-aggregate: out[d] = dinv[d] * sum xw[src] + bias ----------
// Latency-bound gather: UNR independent edge-groups issued back-to-back for MLP.
// Invalid slots gather row N (zeroed by gemm epilogue) -> no mask math.
template <int D, bool RELU, typename OT>
__global__ __launch_bounds__(256) void aggregate_k(const __half* __restrict__ xw,
                                                   const int* __restrict__ ptr,
                                                   const int* __restrict__ meta,
                                                   const float* __restrict__ bias,
                                                   const float* __restrict__ dinv,
                                                   OT* __restrict__ out, int n) {
    constexpr int GS = D / 8;    // lanes per row (16 or 8)
    constexpr int EPW = 64 / GS; // edges per wave-load (4 or 8)
    constexpr int UNR = (EPW == 4) ? 4 : 2;  // groups in flight (step = 16 edges)
    __shared__ int smeta[4][64];
    int lane = threadIdx.x & 63;
    int wid = threadIdx.x >> 6;
    int node = blockIdx.x * 4 + wid;
    if (node >= n) return;
    int e0 = ptr[node], e1 = ptr[node + 1];
    float dv = dinv[node];
    int sub = lane / GS;   // edge sub-slot
    int cg = lane % GS;    // column group: cols [cg*8, cg*8+8)
    const _Float16* xp = (const _Float16*)xw + cg * 8;
    float acc[8];
#pragma unroll
    for (int i = 0; i < 8; i++) acc[i] = 0.f;

    for (int base = e0; base < e1; base += 64) {
        int cnt = min(e1 - base, 64);
        if (lane < cnt) smeta[wid][lane] = meta[base + lane];
        for (int j = 0; j < cnt; j += UNR * EPW) {
            int sreg[UNR];
#pragma unroll
            for (int u = 0; u < UNR; u++) {
                int e = j + u * EPW + sub;  // e <= 63 structurally
                int t = smeta[wid][e];
                sreg[u] = (e < cnt) ? t : n;  // row n = zero row
            }
            half8 vreg[UNR];
#pragma unroll
            for (int u = 0; u < UNR; u++)
                vreg[u] = *(const half8*)(xp + (size_t)sreg[u] * D);
#pragma unroll
            for (int u = 0; u < UNR; u++)
#pragma unroll
                for (int i = 0; i < 8; i++)
                    acc[i] += (float)vreg[u][i];
        }
    }
#pragma unroll
    for (int off = GS; off < 64; off <<= 1) {
#pragma unroll
        for (int i = 0; i < 8; i++) acc[i] += __shfl_xor(acc[i], off, 64);
    }
    if (lane < GS) {
        float4 bb0 = *(const float4*)(bias + cg * 8);
        float4 bb1 = *(const float4*)(bias + cg * 8 + 4);
        float r[8];
        r[0] = acc[0] * dv + bb0.x; r[1] = acc[1] * dv + bb0.y;
        r[2] = acc[2] * dv + bb0.z; r[3] = acc[3] * dv + bb0.w;
        r[4] = acc[4] * dv + bb1.x; r[5] = acc[5] * dv + bb1.y;
        r[6] = acc[6] * dv + bb1.z; r[7] = acc[7] * dv + bb1.w;
        if (RELU) {
#pragma unroll
            for (int i = 0; i < 8; i++) r[i] = fmaxf(r[i], 0.f);
        }
        if constexpr (sizeof(OT) == 2) {
            half8 h;
#pragma unroll
            for (int i = 0; i < 8; i++) h[i] = (_Float16)r[i];
            *(half8*)((_Float16*)out + (size_t)node * D + cg * 8) = h;
        } else {
            float* op = (float*)out + (size_t)node * D + cg * 8;
            *(float4*)op = make_float4(r[0], r[1], r[2], r[3]);
            *(float4*)(op + 4) = make_float4(r[4], r[5], r[6], r[7]);
        }
    }
}

extern "C" void kernel_launch(void* const* d_in, const int* in_sizes, int n_in,
                              void* d_out, int out_size, void* d_ws, size_t ws_size,
                              hipStream_t stream) {
    const float* x = (const float*)d_in[0];
    const int* ei = (const int*)d_in[1];
    const float* W1 = (const float*)d_in[2];
    const float* b1 = (const float*)d_in[3];
    const float* W2 = (const float*)d_in[4];
    const float* b2 = (const float*)d_in[5];
    const float* W3 = (const float*)d_in[6];
    const float* b3 = (const float*)d_in[7];
    float* out = (float*)d_out;
    int N = in_sizes[0] / 128;
    int E = in_sizes[1] / 2;
    const int* row = ei;
    const int* col = ei + E;
    int T = E + N;

    char* w = (char*)d_ws;
    size_t off = 0;
    auto alloc = [&](size_t bytes) -> void* {
        void* p = w + off;
        off = (off + bytes + 511) & ~(size_t)511;
        return p;
    };
    __half* bufH = (__half*)alloc((size_t)(N + 1) * 128 * 2);  // xw + zero row N
    __half* bufA = (__half*)alloc((size_t)N * 128 * 2);        // hidden h
    __half* Wt1 = (__half*)alloc(16384 * 2);
    __half* Wt2 = (__half*)alloc(16384 * 2);
    __half* Wt3 = (__half*)alloc(8192 * 2);
    int* deg = (int*)alloc((size_t)N * 4);
    float* dinv = (float*)alloc((size_t)N * 4);
    int* cptr = (int*)alloc((size_t)(N + 1) * 4);
    int* meta = (int*)alloc((size_t)T * 4);
    int* csum = (int*)alloc(NCH * 4);
    int* ovfcnt = (int*)alloc(64);
    unsigned long long* ovf = (unsigned long long*)alloc((size_t)OVFCAP * 8);
    int NB = (E + TILE - 1) / TILE;              // 782 for E=1.6M (<= MAXNB)
    int* cnts = (int*)alloc((size_t)NCH * NB * 4);
    int chunk = (N + NCH - 1) / NCH;             // 782 for N=100K (<= MAXCH)

    // staging aliases bufH+bufA (2x19.2MB): dead before gemm1 (stream order);
    // row N of bufH (at 25.6MB offset) is outside stg_d's 19.2MB.
    int* stg_d = (int*)bufH;
    int* stg_s = (int*)bufA;

    wconv_k<<<161, 256, 0, stream>>>(W1, W2, W3, Wt1, Wt2, Wt3, ovfcnt);
    part_k<<<NB, 256, 0, stream>>>(row, col, E, chunk, NB, stg_d, stg_s, cnts, ovf, ovfcnt);
    csr_hist_k<<<NCH, 512, 0, stream>>>(stg_d, cnts, NB, N, chunk, ovf, ovfcnt, deg, dinv, csum);
    csr_fill_k<<<NCH, 512, 0, stream>>>(stg_d, stg_s, cnts, NB, deg, csum, N, chunk, ovf,
                                        ovfcnt, cptr, meta);

    int gb = (N + 127) / 128;
    int ab = (N + 3) / 4;
    gemm_mfma<float, 128><<<gb, 256, 0, stream>>>(x, Wt1, dinv, bufH, N);
    aggregate_k<128, true, __half><<<ab, 256, 0, stream>>>(bufH, cptr, meta, b1, dinv, bufA, N);
    gemm_mfma<__half, 128><<<gb, 256, 0, stream>>>(bufA, Wt2, dinv, bufH, N);
    aggregate_k<128, true, __half><<<ab, 256, 0, stream>>>(bufH, cptr, meta, b2, dinv, bufA, N);
    gemm_mfma<__half, 64><<<gb, 256, 0, stream>>>(bufA, Wt3, dinv, bufH, N);
    aggregate_k<64, false, float><<<ab, 256, 0, stream>>>(bufH, cptr, meta, b3, dinv, out, N);
}

// Round 7
// 371.733 us; speedup vs baseline: 1.3201x; 1.0119x over previous
//
#include <hip/hip_runtime.h>
#include <hip/hip_fp16.h>

typedef _Float16 half8 __attribute__((ext_vector_type(8)));
typedef float floatx4 __attribute__((ext_vector_type(4)));

#define NCH 128      // dst chunks (one csr block per chunk)
#define TILE 2048    // edges per part_k block
#define CSLOT 48     // slots per (chunk,block) cell: mean 16, +8 sigma
#define MAXNB 1024   // max part_k blocks supported (E <= 2M)
#define MAXCH 1024   // max nodes per chunk supported (N <= 128K)
#define OVFCAP 65536 // overflow spill capacity (pairs)
#define AGG_GRID 2048 // persistent aggregate blocks (8/CU x 256 CU)

// ---------------- pass 1: partition + fused weight-transpose ----------------
// wconv work (41K elements) rides along in the first 161 blocks before the
// partition phase (independent memory). Deterministic-cell partition:
// NO global atomics (R2==R3 proved scattered atomicAdd(deg) was the 100us cost).
__global__ __launch_bounds__(256) void part_k(const int* __restrict__ row,
                                              const int* __restrict__ col, int E,
                                              int chunk, int NB,
                                              int* __restrict__ stg_d,
                                              int* __restrict__ stg_s,
                                              int* __restrict__ cnts,
                                              unsigned long long* __restrict__ ovf,
                                              int* __restrict__ ovfcnt,
                                              const float* __restrict__ W1,
                                              const float* __restrict__ W2,
                                              const float* __restrict__ W3,
                                              __half* __restrict__ Wt1,
                                              __half* __restrict__ Wt2,
                                              __half* __restrict__ Wt3) {
    __shared__ int bd[NCH][CSLOT];
    __shared__ int bs[NCH][CSLOT];
    __shared__ int lcnt[NCH];
    __shared__ int lpref[NCH + 1];
    int tid = threadIdx.x;
    int b = blockIdx.x;

    // fused weight convert+transpose
    int idx = b * 256 + tid;
    if (idx < 16384) {
        int k = idx >> 7, nn = idx & 127;
        Wt1[nn * 128 + k] = __float2half(W1[idx]);
    } else if (idx < 32768) {
        int j = idx - 16384;
        int k = j >> 7, nn = j & 127;
        Wt2[nn * 128 + k] = __float2half(W2[j]);
    } else if (idx < 40960) {
        int j = idx - 32768;
        int k = j >> 6, nn = j & 63;
        Wt3[nn * 128 + k] = __float2half(W3[j]);
    }

    for (int i = tid; i < NCH; i += 256) lcnt[i] = 0;
    __syncthreads();

    int i0 = b * TILE + tid * 8;
    int sv[8], dv[8];
    int nv = 0;
    if (i0 + 7 < E && (E & 3) == 0) {  // col = ei+E stays 16B-aligned iff E%4==0
        int4 r0 = *(const int4*)(row + i0);
        int4 r1 = *(const int4*)(row + i0 + 4);
        int4 c0 = *(const int4*)(col + i0);
        int4 c1 = *(const int4*)(col + i0 + 4);
        sv[0] = r0.x; sv[1] = r0.y; sv[2] = r0.z; sv[3] = r0.w;
        sv[4] = r1.x; sv[5] = r1.y; sv[6] = r1.z; sv[7] = r1.w;
        dv[0] = c0.x; dv[1] = c0.y; dv[2] = c0.z; dv[3] = c0.w;
        dv[4] = c1.x; dv[5] = c1.y; dv[6] = c1.z; dv[7] = c1.w;
        nv = 8;
    } else {
#pragma unroll
        for (int j = 0; j < 8; j++) {
            if (i0 + j < E) { sv[nv] = row[i0 + j]; dv[nv] = col[i0 + j]; nv++; }
        }
    }
#pragma unroll 8
    for (int j = 0; j < nv; j++) {
        int d = dv[j], s = sv[j];
        int c = d / chunk;  // exact integer binning (must match csr chunk ranges)
        int r = atomicAdd(&lcnt[c], 1);
        if (r < CSLOT) {
            bd[c][r] = d;
            bs[c][r] = s;
        } else {  // ~1e-17/cell; correctness guard
            int o = atomicAdd(ovfcnt, 1);
            if (o < OVFCAP)
                ovf[o] = ((unsigned long long)(unsigned)d << 32) | (unsigned)s;
        }
    }
    __syncthreads();
    if (tid == 0) {
        int a = 0;
#pragma unroll
        for (int c = 0; c < NCH; c++) {
            lpref[c] = a;
            a += min(lcnt[c], CSLOT);
        }
        lpref[NCH] = a;
    }
    __syncthreads();
    for (int c = tid; c < NCH; c += 256) cnts[(size_t)c * NB + b] = min(lcnt[c], CSLOT);
    int total = lpref[NCH];
    for (int f = tid; f < total; f += 256) {
        int lo = 0, hi = NCH;  // binary search: largest c with lpref[c] <= f
        while (hi - lo > 1) {
            int mid = (lo + hi) >> 1;
            if (lpref[mid] <= f) lo = mid; else hi = mid;
        }
        int slot = f - lpref[lo];
        size_t cell = ((size_t)lo * NB + b) * CSLOT;
        stg_d[cell + slot] = bd[lo][slot];
        stg_s[cell + slot] = bs[lo][slot];
    }
}

// ---------------- pass 2a: per-chunk degree histogram + deg/dinv + chunk sums ----
__global__ __launch_bounds__(512) void csr_hist_k(const int* __restrict__ stg_d,
                                                  const int* __restrict__ cnts, int NB,
                                                  int N, int chunk,
                                                  const unsigned long long* __restrict__ ovf,
                                                  const int* __restrict__ ovfcnt,
                                                  int* __restrict__ deg,
                                                  float* __restrict__ dinv,
                                                  int* __restrict__ csum) {
    __shared__ int hist[MAXCH];
    __shared__ int red[512];
    int c = blockIdx.x, tid = threadIdx.x;
    int dlo = c * chunk;
    int dhi = min(N, dlo + chunk);
    int csz = dhi - dlo;
    if (csz <= 0) {
        if (tid == 0) csum[c] = 0;
        return;
    }
    for (int i = tid; i < csz; i += 512) hist[i] = 1;  // self-loop
    __syncthreads();
    for (int b0 = tid >> 4; b0 < NB; b0 += 32) {
        int cnt = cnts[(size_t)c * NB + b0];
        size_t base = ((size_t)c * NB + b0) * CSLOT;
        for (int slot = tid & 15; slot < cnt; slot += 16)
            atomicAdd(&hist[stg_d[base + slot] - dlo], 1);
    }
    int oc = min(*ovfcnt, OVFCAP);
    for (int i = tid; i < oc; i += 512) {
        int d = (int)(ovf[i] >> 32);
        if (d >= dlo && d < dhi) atomicAdd(&hist[d - dlo], 1);
    }
    __syncthreads();
    int t = 0;
    for (int i = tid; i < csz; i += 512) {
        int dg = hist[i];
        deg[dlo + i] = dg;
        dinv[dlo + i] = rsqrtf((float)dg);
        t += dg;
    }
    red[tid] = t;
    __syncthreads();
    for (int o = 256; o > 0; o >>= 1) {
        if (tid < o) red[tid] += red[tid + o];
        __syncthreads();
    }
    if (tid == 0) csum[c] = red[0];
}

// ---------------- pass 2b: per-chunk scan + scatter (NO global atomics) ----------
__global__ __launch_bounds__(512) void csr_fill_k(const int* __restrict__ stg_d,
                                                  const int* __restrict__ stg_s,
                                                  const int* __restrict__ cnts, int NB,
                                                  const int* __restrict__ deg,
                                                  const int* __restrict__ csum,
                                                  int N, int chunk,
                                                  const unsigned long long* __restrict__ ovf,
                                                  const int* __restrict__ ovfcnt,
                                                  int* __restrict__ cptr,
                                                  int* __restrict__ meta) {
    __shared__ int cur[MAXCH];
    __shared__ int sc[512];
    int c = blockIdx.x, tid = threadIdx.x;
    int dlo = c * chunk;
    int dhi = min(N, dlo + chunk);
    int csz = dhi - dlo;
    if (csz <= 0) return;

    // chunk base = sum of csum[0..c)
    sc[tid] = (tid < NCH && tid < c) ? csum[tid] : 0;
    __syncthreads();
    for (int o = 256; o > 0; o >>= 1) {
        if (tid < o) sc[tid] += sc[tid + o];
        __syncthreads();
    }
    int cbase = sc[0];
    __syncthreads();

    // local exclusive scan of deg slice (2 elems/thread)
    int i0 = tid * 2;
    int v0 = (i0 < csz) ? deg[dlo + i0] : 0;
    int v1 = (i0 + 1 < csz) ? deg[dlo + i0 + 1] : 0;
    int s = v0 + v1;
    sc[tid] = s;
    __syncthreads();
    for (int o = 1; o < 512; o <<= 1) {
        int tmp = 0;
        if (tid >= o) tmp = sc[tid - o];
        __syncthreads();
        sc[tid] += tmp;
        __syncthreads();
    }
    int off = cbase + sc[tid] - s;  // exclusive prefix
    if (i0 < csz) {
        cur[i0] = off;
        cptr[dlo + i0] = off;
        off += v0;
        if (i0 + 1 < csz) {
            cur[i0 + 1] = off;
            cptr[dlo + i0 + 1] = off;
        }
    }
    if (dhi == N && tid == 511) cptr[N] = cbase + sc[511];  // total end
    __syncthreads();

    // place staged pairs
    for (int b0 = tid >> 4; b0 < NB; b0 += 32) {
        int cnt = cnts[(size_t)c * NB + b0];
        size_t base = ((size_t)c * NB + b0) * CSLOT;
        for (int slot = tid & 15; slot < cnt; slot += 16) {
            int d = stg_d[base + slot];
            int sv = stg_s[base + slot];
            int p = atomicAdd(&cur[d - dlo], 1);
            meta[p] = sv;
        }
    }
    // self-loops
    for (int i = tid; i < csz; i += 512) {
        int p = atomicAdd(&cur[i], 1);
        meta[p] = dlo + i;
    }
    // overflow spills (normally zero)
    int oc = min(*ovfcnt, OVFCAP);
    for (int i = tid; i < oc; i += 512) {
        unsigned long long v = ovf[i];
        int d = (int)(v >> 32);
        if (d >= dlo && d < dhi) {
            int p = atomicAdd(&cur[d - dlo], 1);
            meta[p] = (int)(v & 0xffffffffull);
        }
    }
}

// ---------------- f16 MFMA GEMM: C[n][DOUT] = (half)(dinv[r] * A[n][128] @ W) ------
// Epilogue also zeroes row n of C (the aggregate's "zero row" for padded slots).
template <typename AT, int DOUT>
__global__ __launch_bounds__(256) void gemm_mfma(const AT* __restrict__ A,
                                                 const __half* __restrict__ Wt,
                                                 const float* __restrict__ dinv,
                                                 __half* __restrict__ C, int n) {
    constexpr int CT = DOUT / 16;  // col tiles: 8 or 4
    constexpr int WP = 136;        // padded LDS stride (halves)
    __shared__ _Float16 ldsW[DOUT * WP];
    int tid = threadIdx.x;
    int lane = tid & 63;
    int wid = tid >> 6;
    for (int i = tid; i < DOUT * 16; i += 256) {
        int nrow = i >> 4;
        int kc = (i & 15) * 8;
        *(half8*)(&ldsW[nrow * WP + kc]) =
            *(const half8*)((const _Float16*)Wt + nrow * 128 + kc);
    }
    __syncthreads();
    int rwb = blockIdx.x * 128 + wid * 32;
    int m = lane & 15;
    int quad = lane >> 4;
    floatx4 acc[2][CT];
#pragma unroll
    for (int t = 0; t < 2; t++)
#pragma unroll
        for (int c = 0; c < CT; c++) acc[t][c] = (floatx4){0.f, 0.f, 0.f, 0.f};

#pragma unroll
    for (int kq = 0; kq < 4; kq++) {
        int k0 = kq * 32 + quad * 8;
        half8 afr[2];
#pragma unroll
        for (int t = 0; t < 2; t++) {
            int r = rwb + t * 16 + m;
            r = r < n ? r : n - 1;  // clamp (results unused for OOB rows)
            const AT* ap = A + (size_t)r * 128 + k0;
            if constexpr (sizeof(AT) == 2) {
                afr[t] = *(const half8*)ap;
            } else {
                float4 f0 = *(const float4*)ap;
                float4 f1 = *(const float4*)(ap + 4);
                half8 h;
                h[0] = (_Float16)f0.x; h[1] = (_Float16)f0.y;
                h[2] = (_Float16)f0.z; h[3] = (_Float16)f0.w;
                h[4] = (_Float16)f1.x; h[5] = (_Float16)f1.y;
                h[6] = (_Float16)f1.z; h[7] = (_Float16)f1.w;
                afr[t] = h;
            }
        }
#pragma unroll
        for (int c = 0; c < CT; c++) {
            half8 bfr = *(const half8*)(&ldsW[(c * 16 + m) * WP + k0]);
#pragma unroll
            for (int t = 0; t < 2; t++)
                acc[t][c] =
                    __builtin_amdgcn_mfma_f32_16x16x32_f16(afr[t], bfr, acc[t][c], 0, 0, 0);
        }
    }
#pragma unroll
    for (int t = 0; t < 2; t++) {
#pragma unroll
        for (int reg = 0; reg < 4; reg++) {
            int r = rwb + t * 16 + quad * 4 + reg;
            if (r < n) {
                float dv = dinv[r];
#pragma unroll
                for (int c = 0; c < CT; c++)
                    C[(size_t)r * DOUT + c * 16 + m] = __float2half(acc[t][c][reg] * dv);
            }
        }
    }
    if (blockIdx.x == 0 && tid < DOUT / 8) {  // zero row n (aggregate pad target)
        half8 z = (half8){0, 0, 0, 0, 0, 0, 0, 0};
        *(half8*)((_Float16*)C + (size_t)n * DOUT + tid * 8) = z;
    }
}

// ---------------- gather-aggregate: out[d] = dinv[d] * sum xw[src] + bias ----------
// Persistent grid-stride waves (R6: 25K short-lived blocks left occupancy at 72% --
// wave slots idle on block dispatch; 2048 resident blocks keep 32 waves/CU fed to
// maximize in-flight L2-fill misses). UNR independent gathers per step for MLP;
// invalid slots gather row n (zeroed by gemm epilogue).
template <int D, bool RELU, typename OT>
__global__ __launch_bounds__(256) void aggregate_k(const __half* __restrict__ xw,
                                                   const int* __restrict__ ptr,
                                                   const int* __restrict__ meta,
                                                   const float* __restrict__ bias,
                                                   const float* __restrict__ dinv,
                                                   OT* __restrict__ out, int n) {
    constexpr int GS = D / 8;    // lanes per row (16 or 8)
    constexpr int EPW = 64 / GS; // edges per wave-load (4 or 8)
    constexpr int UNR = 4;       // gather groups in flight
    __shared__ int smeta[4][64];
    int lane = threadIdx.x & 63;
    int wid = threadIdx.x >> 6;
    int sub = lane / GS;   // edge sub-slot
    int cg = lane % GS;    // column group: cols [cg*8, cg*8+8)
    const _Float16* xp = (const _Float16*)xw + cg * 8;

    for (int node = blockIdx.x * 4 + wid; node < n; node += gridDim.x * 4) {
        int e0 = ptr[node], e1 = ptr[node + 1];
        float dv = dinv[node];
        float acc[8];
#pragma unroll
        for (int i = 0; i < 8; i++) acc[i] = 0.f;

        for (int base = e0; base < e1; base += 64) {
            int cnt = min(e1 - base, 64);
            if (lane < cnt) smeta[wid][lane] = meta[base + lane];
            for (int j = 0; j < cnt; j += UNR * EPW) {
                int sreg[UNR];
#pragma unroll
                for (int u = 0; u < UNR; u++) {
                    int e = j + u * EPW + sub;
                    e = (e < 64) ? e : 0;  // keep smeta index in range (D=64 case)
                    int t = smeta[wid][e];
                    sreg[u] = (j + u * EPW + sub < cnt) ? t : n;  // row n = zero row
                }
                half8 vreg[UNR];
#pragma unroll
                for (int u = 0; u < UNR; u++)
                    vreg[u] = *(const half8*)(xp + (size_t)sreg[u] * D);
#pragma unroll
                for (int u = 0; u < UNR; u++)
#pragma unroll
                    for (int i = 0; i < 8; i++)
                        acc[i] += (float)vreg[u][i];
            }
        }
#pragma unroll
        for (int off = GS; off < 64; off <<= 1) {
#pragma unroll
            for (int i = 0; i < 8; i++) acc[i] += __shfl_xor(acc[i], off, 64);
        }
        if (lane < GS) {
            float4 bb0 = *(const float4*)(bias + cg * 8);
            float4 bb1 = *(const float4*)(bias + cg * 8 + 4);
            float r[8];
            r[0] = acc[0] * dv + bb0.x; r[1] = acc[1] * dv + bb0.y;
            r[2] = acc[2] * dv + bb0.z; r[3] = acc[3] * dv + bb0.w;
            r[4] = acc[4] * dv + bb1.x; r[5] = acc[5] * dv + bb1.y;
            r[6] = acc[6] * dv + bb1.z; r[7] = acc[7] * dv + bb1.w;
            if (RELU) {
#pragma unroll
                for (int i = 0; i < 8; i++) r[i] = fmaxf(r[i], 0.f);
            }
            if constexpr (sizeof(OT) == 2) {
                half8 h;
#pragma unroll
                for (int i = 0; i < 8; i++) h[i] = (_Float16)r[i];
                *(half8*)((_Float16*)out + (size_t)node * D + cg * 8) = h;
            } else {
                float* op = (float*)out + (size_t)node * D + cg * 8;
                *(float4*)op = make_float4(r[0], r[1], r[2], r[3]);
                *(float4*)(op + 4) = make_float4(r[4], r[5], r[6], r[7]);
            }
        }
    }
}

extern "C" void kernel_launch(void* const* d_in, const int* in_sizes, int n_in,
                              void* d_out, int out_size, void* d_ws, size_t ws_size,
                              hipStream_t stream) {
    const float* x = (const float*)d_in[0];
    const int* ei = (const int*)d_in[1];
    const float* W1 = (const float*)d_in[2];
    const float* b1 = (const float*)d_in[3];
    const float* W2 = (const float*)d_in[4];
    const float* b2 = (const float*)d_in[5];
    const float* W3 = (const float*)d_in[6];
    const float* b3 = (const float*)d_in[7];
    float* out = (float*)d_out;
    int N = in_sizes[0] / 128;
    int E = in_sizes[1] / 2;
    const int* row = ei;
    const int* col = ei + E;
    int T = E + N;

    char* w = (char*)d_ws;
    size_t off = 0;
    auto alloc = [&](size_t bytes) -> void* {
        void* p = w + off;
        off = (off + bytes + 511) & ~(size_t)511;
        return p;
    };
    __half* bufH = (__half*)alloc((size_t)(N + 1) * 128 * 2);  // xw + zero row N
    __half* bufA = (__half*)alloc((size_t)N * 128 * 2);        // hidden h
    __half* Wt1 = (__half*)alloc(16384 * 2);
    __half* Wt2 = (__half*)alloc(16384 * 2);
    __half* Wt3 = (__half*)alloc(8192 * 2);
    int* deg = (int*)alloc((size_t)N * 4);
    float* dinv = (float*)alloc((size_t)N * 4);
    int* cptr = (int*)alloc((size_t)(N + 1) * 4);
    int* meta = (int*)alloc((size_t)T * 4);
    int* csum = (int*)alloc(NCH * 4);
    int* ovfcnt = (int*)alloc(64);
    unsigned long long* ovf = (unsigned long long*)alloc((size_t)OVFCAP * 8);
    int NB = (E + TILE - 1) / TILE;              // 782 for E=1.6M (<= MAXNB)
    int* cnts = (int*)alloc((size_t)NCH * NB * 4);
    int chunk = (N + NCH - 1) / NCH;             // 782 for N=100K (<= MAXCH)

    // staging aliases bufH+bufA: dead before gemm1 (stream order);
    // row N of bufH (at 25.6MB offset) is outside stg_d's 19.2MB.
    int* stg_d = (int*)bufH;
    int* stg_s = (int*)bufA;

    hipMemsetAsync(ovfcnt, 0, 4, stream);
    part_k<<<NB, 256, 0, stream>>>(row, col, E, chunk, NB, stg_d, stg_s, cnts, ovf, ovfcnt,
                                   W1, W2, W3, Wt1, Wt2, Wt3);
    csr_hist_k<<<NCH, 512, 0, stream>>>(stg_d, cnts, NB, N, chunk, ovf, ovfcnt, deg, dinv, csum);
    csr_fill_k<<<NCH, 512, 0, stream>>>(stg_d, stg_s, cnts, NB, deg, csum, N, chunk, ovf,
                                        ovfcnt, cptr, meta);

    int gb = (N + 127) / 128;
    gemm_mfma<float, 128><<<gb, 256, 0, stream>>>(x, Wt1, dinv, bufH, N);
    aggregate_k<128, true, __half><<<AGG_GRID, 256, 0, stream>>>(bufH, cptr, meta, b1, dinv, bufA, N);
    gemm_mfma<__half, 128><<<gb, 256, 0, stream>>>(bufA, Wt2, dinv, bufH, N);
    aggregate_k<128, true, __half><<<AGG_GRID, 256, 0, stream>>>(bufH, cptr, meta, b2, dinv, bufA, N);
    gemm_mfma<__half, 64><<<gb, 256, 0, stream>>>(bufA, Wt3, dinv, bufH, N);
    aggregate_k<64, false, float><<<AGG_GRID, 256, 0, stream>>>(bufH, cptr, meta, b3, dinv, out, N);
}

// Round 8
// 366.142 us; speedup vs baseline: 1.3402x; 1.0153x over previous
//
#include <hip/hip_runtime.h>
#include <hip/hip_fp16.h>

typedef _Float16 half8 __attribute__((ext_vector_type(8)));
typedef float floatx4 __attribute__((ext_vector_type(4)));
typedef unsigned long long u64;

#define NCH 128      // dst chunks (one csr block per chunk)
#define TILE 2048    // edges per part_k block
#define CSLOT 48     // slots per (chunk,block) cell: mean 16, +8 sigma
#define MAXCH2 800   // max nodes per chunk (N <= 102.4K)
#define PLCAP 14336  // LDS pair-stash cap (mean 12512, sigma 112 -> +16 sigma)
#define OVFCAP 65536 // overflow spill capacity (pairs)
#define AGG_GRID 2048 // persistent aggregate blocks (8/CU x 256 CU)

// ---------------- pass 1: partition + fused weight-transpose ----------------
// Deterministic-cell partition into packed (d,s) u64 staging. NO per-edge global
// atomics (R2==R3 proved scattered atomicAdd was the 100us cost). Per-chunk cell
// counts also accumulate into line-padded chunkTot[] (782 adds/line ~2us) so
// csr_build can compute chunk bases without a separate scan kernel.
__global__ __launch_bounds__(256) void part_k(const int* __restrict__ row,
                                              const int* __restrict__ col, int E,
                                              int chunk, int NB,
                                              u64* __restrict__ stg_p,
                                              int* __restrict__ cnts,
                                              int* __restrict__ chunkTot,
                                              u64* __restrict__ ovf,
                                              int* __restrict__ ovfcnt,
                                              const float* __restrict__ W1,
                                              const float* __restrict__ W2,
                                              const float* __restrict__ W3,
                                              __half* __restrict__ Wt1,
                                              __half* __restrict__ Wt2,
                                              __half* __restrict__ Wt3) {
    __shared__ u64 bkt[NCH][CSLOT];
    __shared__ int lcnt[NCH];
    __shared__ int lpref[NCH + 1];
    int tid = threadIdx.x;
    int b = blockIdx.x;

    // fused weight convert+transpose (first 161 blocks)
    int idx = b * 256 + tid;
    if (idx < 16384) {
        int k = idx >> 7, nn = idx & 127;
        Wt1[nn * 128 + k] = __float2half(W1[idx]);
    } else if (idx < 32768) {
        int j = idx - 16384;
        int k = j >> 7, nn = j & 127;
        Wt2[nn * 128 + k] = __float2half(W2[j]);
    } else if (idx < 40960) {
        int j = idx - 32768;
        int k = j >> 6, nn = j & 63;
        Wt3[nn * 128 + k] = __float2half(W3[j]);
    }

    for (int i = tid; i < NCH; i += 256) lcnt[i] = 0;
    __syncthreads();

    int i0 = b * TILE + tid * 8;
    int sv[8], dv[8];
    int nv = 0;
    if (i0 + 7 < E && (E & 3) == 0) {  // col = ei+E stays 16B-aligned iff E%4==0
        int4 r0 = *(const int4*)(row + i0);
        int4 r1 = *(const int4*)(row + i0 + 4);
        int4 c0 = *(const int4*)(col + i0);
        int4 c1 = *(const int4*)(col + i0 + 4);
        sv[0] = r0.x; sv[1] = r0.y; sv[2] = r0.z; sv[3] = r0.w;
        sv[4] = r1.x; sv[5] = r1.y; sv[6] = r1.z; sv[7] = r1.w;
        dv[0] = c0.x; dv[1] = c0.y; dv[2] = c0.z; dv[3] = c0.w;
        dv[4] = c1.x; dv[5] = c1.y; dv[6] = c1.z; dv[7] = c1.w;
        nv = 8;
    } else {
#pragma unroll
        for (int j = 0; j < 8; j++) {
            if (i0 + j < E) { sv[nv] = row[i0 + j]; dv[nv] = col[i0 + j]; nv++; }
        }
    }
#pragma unroll 8
    for (int j = 0; j < nv; j++) {
        int d = dv[j], s = sv[j];
        int c = d / chunk;  // exact integer binning (must match csr chunk ranges)
        int r = atomicAdd(&lcnt[c], 1);
        u64 pair = ((u64)(unsigned)d << 32) | (unsigned)s;
        if (r < CSLOT) {
            bkt[c][r] = pair;
        } else {  // ~1e-17/cell; correctness guard
            int o = atomicAdd(ovfcnt, 1);
            if (o < OVFCAP) ovf[o] = pair;
        }
    }
    __syncthreads();
    if (tid < NCH) {
        int cc = min(lcnt[tid], CSLOT);
        lcnt[tid] = cc;
        cnts[(size_t)tid * NB + b] = cc;
        atomicAdd(&chunkTot[tid * 16], cc);  // 64B-padded per-chunk totals
    }
    __syncthreads();
    if (tid == 0) {
        int a = 0;
#pragma unroll
        for (int c = 0; c < NCH; c++) {
            lpref[c] = a;
            a += lcnt[c];
        }
        lpref[NCH] = a;
    }
    __syncthreads();
    int total = lpref[NCH];
    for (int f = tid; f < total; f += 256) {
        int lo = 0, hi = NCH;  // binary search: largest c with lpref[c] <= f
        while (hi - lo > 1) {
            int mid = (lo + hi) >> 1;
            if (lpref[mid] <= f) lo = mid; else hi = mid;
        }
        int slot = f - lpref[lo];
        stg_p[((size_t)lo * NB + b) * CSLOT + slot] = bkt[lo][slot];
    }
}

// ---------------- pass 2: fused per-chunk hist + scan + scatter ------------------
// One block per chunk, NO global atomics. cbase = dlo (self-loop prefix) +
// sum(chunkTot[<c]) + #(ovf below chunk). Cells are read ONCE: pairs stash into
// LDS (PLCAP, 16-sigma; global-reread fallback) while histogramming; then local
// scan -> dinv/cptr, then scatter meta from the LDS stash.
__global__ __launch_bounds__(512) void csr_build_k(const u64* __restrict__ stg_p,
                                                   const int* __restrict__ cnts,
                                                   const int* __restrict__ chunkTot,
                                                   int NB, int N, int chunk,
                                                   const u64* __restrict__ ovf,
                                                   const int* __restrict__ ovfcnt,
                                                   float* __restrict__ dinv,
                                                   int* __restrict__ cptr,
                                                   int* __restrict__ meta) {
    __shared__ int hist[MAXCH2];
    __shared__ int cur[MAXCH2];
    __shared__ int sc[512];
    __shared__ u64 pl[PLCAP];
    __shared__ int plcnt;
    int c = blockIdx.x, tid = threadIdx.x;
    int dlo = c * chunk;
    int dhi = min(N, dlo + chunk);
    int csz = dhi - dlo;
    if (csz <= 0) return;
    if (tid == 0) plcnt = 0;
    for (int i = tid; i < csz; i += 512) hist[i] = 1;  // self-loop

    // chunk base: prior chunks' totals (64B-padded) + prior self-loops + prior ovf
    int part = 0;
    for (int i = tid; i < c; i += 512) part += chunkTot[i * 16];
    int oc = min(*ovfcnt, OVFCAP);
    for (int i = tid; i < oc; i += 512) {
        int d = (int)(ovf[i] >> 32);
        if (d < dlo) part++;
    }
    sc[tid] = part;
    __syncthreads();
    for (int o = 256; o > 0; o >>= 1) {
        if (tid < o) sc[tid] += sc[tid + o];
        __syncthreads();
    }
    int cbase = dlo + sc[0];
    __syncthreads();

    // read cells once: histogram + LDS stash
    for (int b0 = tid >> 4; b0 < NB; b0 += 32) {
        int cnt = cnts[(size_t)c * NB + b0];
        size_t base = ((size_t)c * NB + b0) * CSLOT;
        for (int slot = tid & 15; slot < cnt; slot += 16) {
            u64 v = stg_p[base + slot];
            atomicAdd(&hist[(int)(v >> 32) - dlo], 1);
            int p = atomicAdd(&plcnt, 1);
            if (p < PLCAP) pl[p] = v;
        }
    }
    for (int i = tid; i < oc; i += 512) {  // own-chunk overflow into hist
        int d = (int)(ovf[i] >> 32);
        if (d >= dlo && d < dhi) atomicAdd(&hist[d - dlo], 1);
    }
    __syncthreads();

    // local exclusive scan (2 elems/thread) -> cur/cptr/dinv
    int i0 = tid * 2;
    int v0 = (i0 < csz) ? hist[i0] : 0;
    int v1 = (i0 + 1 < csz) ? hist[i0 + 1] : 0;
    int s = v0 + v1;
    sc[tid] = s;
    __syncthreads();
    for (int o = 1; o < 512; o <<= 1) {
        int tmp = 0;
        if (tid >= o) tmp = sc[tid - o];
        __syncthreads();
        sc[tid] += tmp;
        __syncthreads();
    }
    int off = cbase + sc[tid] - s;
    if (i0 < csz) {
        cur[i0] = off;
        cptr[dlo + i0] = off;
        dinv[dlo + i0] = rsqrtf((float)v0);
        off += v0;
        if (i0 + 1 < csz) {
            cur[i0 + 1] = off;
            cptr[dlo + i0 + 1] = off;
            dinv[dlo + i0 + 1] = rsqrtf((float)v1);
        }
    }
    if (dhi == N && tid == 511) cptr[N] = cbase + sc[511];
    __syncthreads();

    // scatter from LDS stash (or global fallback if stash overflowed)
    int pc = plcnt;
    if (pc <= PLCAP) {
        for (int i = tid; i < pc; i += 512) {
            u64 v = pl[i];
            int p = atomicAdd(&cur[(int)(v >> 32) - dlo], 1);
            meta[p] = (int)(v & 0xffffffffULL);
        }
    } else {  // astronomically rare: re-read cells
        for (int b0 = tid >> 4; b0 < NB; b0 += 32) {
            int cnt = cnts[(size_t)c * NB + b0];
            size_t base = ((size_t)c * NB + b0) * CSLOT;
            for (int slot = tid & 15; slot < cnt; slot += 16) {
                u64 v = stg_p[base + slot];
                int p = atomicAdd(&cur[(int)(v >> 32) - dlo], 1);
                meta[p] = (int)(v & 0xffffffffULL);
            }
        }
    }
    // self-loops
    for (int i = tid; i < csz; i += 512) {
        int p = atomicAdd(&cur[i], 1);
        meta[p] = dlo + i;
    }
    // overflow spills (normally zero)
    for (int i = tid; i < oc; i += 512) {
        u64 v = ovf[i];
        int d = (int)(v >> 32);
        if (d >= dlo && d < dhi) {
            int p = atomicAdd(&cur[d - dlo], 1);
            meta[p] = (int)(v & 0xffffffffULL);
        }
    }
}

// ---------------- f16 MFMA GEMM: C[n][DOUT] = (half)(dinv[r] * A[n][128] @ W) ------
// Epilogue also zeroes row n of C (the aggregate's "zero row" for padded slots).
template <typename AT, int DOUT>
__global__ __launch_bounds__(256) void gemm_mfma(const AT* __restrict__ A,
                                                 const __half* __restrict__ Wt,
                                                 const float* __restrict__ dinv,
                                                 __half* __restrict__ C, int n) {
    constexpr int CT = DOUT / 16;  // col tiles: 8 or 4
    constexpr int WP = 136;        // padded LDS stride (halves)
    __shared__ _Float16 ldsW[DOUT * WP];
    int tid = threadIdx.x;
    int lane = tid & 63;
    int wid = tid >> 6;
    for (int i = tid; i < DOUT * 16; i += 256) {
        int nrow = i >> 4;
        int kc = (i & 15) * 8;
        *(half8*)(&ldsW[nrow * WP + kc]) =
            *(const half8*)((const _Float16*)Wt + nrow * 128 + kc);
    }
    __syncthreads();
    int rwb = blockIdx.x * 128 + wid * 32;
    int m = lane & 15;
    int quad = lane >> 4;
    floatx4 acc[2][CT];
#pragma unroll
    for (int t = 0; t < 2; t++)
#pragma unroll
        for (int c = 0; c < CT; c++) acc[t][c] = (floatx4){0.f, 0.f, 0.f, 0.f};

#pragma unroll
    for (int kq = 0; kq < 4; kq++) {
        int k0 = kq * 32 + quad * 8;
        half8 afr[2];
#pragma unroll
        for (int t = 0; t < 2; t++) {
            int r = rwb + t * 16 + m;
            r = r < n ? r : n - 1;  // clamp (results unused for OOB rows)
            const AT* ap = A + (size_t)r * 128 + k0;
            if constexpr (sizeof(AT) == 2) {
                afr[t] = *(const half8*)ap;
            } else {
                float4 f0 = *(const float4*)ap;
                float4 f1 = *(const float4*)(ap + 4);
                half8 h;
                h[0] = (_Float16)f0.x; h[1] = (_Float16)f0.y;
                h[2] = (_Float16)f0.z; h[3] = (_Float16)f0.w;
                h[4] = (_Float16)f1.x; h[5] = (_Float16)f1.y;
                h[6] = (_Float16)f1.z; h[7] = (_Float16)f1.w;
                afr[t] = h;
            }
        }
#pragma unroll
        for (int c = 0; c < CT; c++) {
            half8 bfr = *(const half8*)(&ldsW[(c * 16 + m) * WP + k0]);
#pragma unroll
            for (int t = 0; t < 2; t++)
                acc[t][c] =
                    __builtin_amdgcn_mfma_f32_16x16x32_f16(afr[t], bfr, acc[t][c], 0, 0, 0);
        }
    }
#pragma unroll
    for (int t = 0; t < 2; t++) {
#pragma unroll
        for (int reg = 0; reg < 4; reg++) {
            int r = rwb + t * 16 + quad * 4 + reg;
            if (r < n) {
                float dv = dinv[r];
#pragma unroll
                for (int c = 0; c < CT; c++)
                    C[(size_t)r * DOUT + c * 16 + m] = __float2half(acc[t][c][reg] * dv);
            }
        }
    }
    if (blockIdx.x == 0 && tid < DOUT / 8) {  // zero row n (aggregate pad target)
        half8 z = (half8){0, 0, 0, 0, 0, 0, 0, 0};
        *(half8*)((_Float16*)C + (size_t)n * DOUT + tid * 8) = z;
    }
}

// ---------------- gather-aggregate: out[d] = dinv[d] * sum xw[src] + bias ----------
// At the structural L2-fill floor (8 XCDs x table bytes; ~85% of the ~450GB/s/XCD
// fill ceiling -- R5/R7 proved insensitive to MLP depth & occupancy). Persistent
// grid-stride waves; UNR independent gathers per step; invalid slots gather row n
// (zeroed by gemm epilogue).
template <int D, bool RELU, typename OT>
__global__ __launch_bounds__(256) void aggregate_k(const __half* __restrict__ xw,
                                                   const int* __restrict__ ptr,
                                                   const int* __restrict__ meta,
                                                   const float* __restrict__ bias,
                                                   const float* __restrict__ dinv,
                                                   OT* __restrict__ out, int n) {
    constexpr int GS = D / 8;    // lanes per row (16 or 8)
    constexpr int EPW = 64 / GS; // edges per wave-load (4 or 8)
    constexpr int UNR = 4;       // gather groups in flight
    __shared__ int smeta[4][64];
    int lane = threadIdx.x & 63;
    int wid = threadIdx.x >> 6;
    int sub = lane / GS;   // edge sub-slot
    int cg = lane % GS;    // column group: cols [cg*8, cg*8+8)
    const _Float16* xp = (const _Float16*)xw + cg * 8;

    for (int node = blockIdx.x * 4 + wid; node < n; node += gridDim.x * 4) {
        int e0 = ptr[node], e1 = ptr[node + 1];
        float dv = dinv[node];
        float acc[8];
#pragma unroll
        for (int i = 0; i < 8; i++) acc[i] = 0.f;

        for (int base = e0; base < e1; base += 64) {
            int cnt = min(e1 - base, 64);
            if (lane < cnt) smeta[wid][lane] = meta[base + lane];
            for (int j = 0; j < cnt; j += UNR * EPW) {
                int sreg[UNR];
#pragma unroll
                for (int u = 0; u < UNR; u++) {
                    int e = j + u * EPW + sub;  // provably <= 63
                    int t = smeta[wid][e];
                    sreg[u] = (e < cnt) ? t : n;  // row n = zero row
                }
                half8 vreg[UNR];
#pragma unroll
                for (int u = 0; u < UNR; u++)
                    vreg[u] = *(const half8*)(xp + (size_t)sreg[u] * D);
#pragma unroll
                for (int u = 0; u < UNR; u++)
#pragma unroll
                    for (int i = 0; i < 8; i++)
                        acc[i] += (float)vreg[u][i];
            }
        }
#pragma unroll
        for (int off = GS; off < 64; off <<= 1) {
#pragma unroll
            for (int i = 0; i < 8; i++) acc[i] += __shfl_xor(acc[i], off, 64);
        }
        if (lane < GS) {
            float4 bb0 = *(const float4*)(bias + cg * 8);
            float4 bb1 = *(const float4*)(bias + cg * 8 + 4);
            float r[8];
            r[0] = acc[0] * dv + bb0.x; r[1] = acc[1] * dv + bb0.y;
            r[2] = acc[2] * dv + bb0.z; r[3] = acc[3] * dv + bb0.w;
            r[4] = acc[4] * dv + bb1.x; r[5] = acc[5] * dv + bb1.y;
            r[6] = acc[6] * dv + bb1.z; r[7] = acc[7] * dv + bb1.w;
            if (RELU) {
#pragma unroll
                for (int i = 0; i < 8; i++) r[i] = fmaxf(r[i], 0.f);
            }
            if constexpr (sizeof(OT) == 2) {
                half8 h;
#pragma unroll
                for (int i = 0; i < 8; i++) h[i] = (_Float16)r[i];
                *(half8*)((_Float16*)out + (size_t)node * D + cg * 8) = h;
            } else {
                float* op = (float*)out + (size_t)node * D + cg * 8;
                *(float4*)op = make_float4(r[0], r[1], r[2], r[3]);
                *(float4*)(op + 4) = make_float4(r[4], r[5], r[6], r[7]);
            }
        }
    }
}

extern "C" void kernel_launch(void* const* d_in, const int* in_sizes, int n_in,
                              void* d_out, int out_size, void* d_ws, size_t ws_size,
                              hipStream_t stream) {
    const float* x = (const float*)d_in[0];
    const int* ei = (const int*)d_in[1];
    const float* W1 = (const float*)d_in[2];
    const float* b1 = (const float*)d_in[3];
    const float* W2 = (const float*)d_in[4];
    const float* b2 = (const float*)d_in[5];
    const float* W3 = (const float*)d_in[6];
    const float* b3 = (const float*)d_in[7];
    float* out = (float*)d_out;
    int N = in_sizes[0] / 128;
    int E = in_sizes[1] / 2;
    const int* row = ei;
    const int* col = ei + E;
    int T = E + N;

    char* w = (char*)d_ws;
    size_t off = 0;
    auto alloc = [&](size_t bytes) -> void* {
        void* p = w + off;
        off = (off + bytes + 511) & ~(size_t)511;
        return p;
    };
    __half* bufH = (__half*)alloc((size_t)(N + 1) * 128 * 2);  // xw + zero row N
    __half* bufA = (__half*)alloc((size_t)N * 128 * 2);        // hidden h
    __half* Wt1 = (__half*)alloc(16384 * 2);
    __half* Wt2 = (__half*)alloc(16384 * 2);
    __half* Wt3 = (__half*)alloc(8192 * 2);
    float* dinv = (float*)alloc((size_t)N * 4);
    int* cptr = (int*)alloc((size_t)(N + 1) * 4);
    int* meta = (int*)alloc((size_t)T * 4);
    int* ctblock = (int*)alloc(128 * 64 + 64);  // chunkTot (padded) + ovfcnt
    u64* ovf = (u64*)alloc((size_t)OVFCAP * 8);
    int NB = (E + TILE - 1) / TILE;              // 782 for E=1.6M
    int* cnts = (int*)alloc((size_t)NCH * NB * 4);
    int chunk = (N + NCH - 1) / NCH;             // 782 for N=100K (<= MAXCH2)

    int* chunkTot = ctblock;           // stride-16 ints (64B lines)
    int* ovfcnt = ctblock + 2048;      // byte offset 8192

    // staging aliases the first 38.4MB of workspace (bufH+bufA region): dead
    // before gemm1 (stream order). Row N of bufH (25.6MB offset) is untouched
    // until gemm1 writes it.
    u64* stg_p = (u64*)d_ws;

    hipMemsetAsync(ctblock, 0, 128 * 64 + 64, stream);
    part_k<<<NB, 256, 0, stream>>>(row, col, E, chunk, NB, stg_p, cnts, chunkTot,
                                   ovf, ovfcnt, W1, W2, W3, Wt1, Wt2, Wt3);
    csr_build_k<<<NCH, 512, 0, stream>>>(stg_p, cnts, chunkTot, NB, N, chunk, ovf,
                                         ovfcnt, dinv, cptr, meta);

    int gb = (N + 127) / 128;
    gemm_mfma<float, 128><<<gb, 256, 0, stream>>>(x, Wt1, dinv, bufH, N);
    aggregate_k<128, true, __half><<<AGG_GRID, 256, 0, stream>>>(bufH, cptr, meta, b1, dinv, bufA, N);
    gemm_mfma<__half, 128><<<gb, 256, 0, stream>>>(bufA, Wt2, dinv, bufH, N);
    aggregate_k<128, true, __half><<<AGG_GRID, 256, 0, stream>>>(bufH, cptr, meta, b2, dinv, bufA, N);
    gemm_mfma<__half, 64><<<gb, 256, 0, stream>>>(bufA, Wt3, dinv, bufH, N);
    aggregate_k<64, false, float><<<AGG_GRID, 256, 0, stream>>>(bufH, cptr, meta, b3, dinv, out, N);
}